// Round 14
// baseline (278.553 us; speedup 1.0000x reference)
//
#include <hip/hip_runtime.h>
#include <hip/hip_bf16.h>

typedef __attribute__((ext_vector_type(4))) float f32x4;
typedef __attribute__((ext_vector_type(8))) short bf16x8;

#define LOG2E 1.4426950408889634f

__device__ __forceinline__ unsigned short f2b(float f) {
  union { float f; unsigned u; } v; v.f = f;
  unsigned r = v.u + 0x7fffu + ((v.u >> 16) & 1u);
  return (unsigned short)(r >> 16);
}
__device__ __forceinline__ float b2f(unsigned short s) {
  union { unsigned u; float f; } v; v.u = ((unsigned)s) << 16;
  return v.f;
}
__device__ __forceinline__ unsigned cvtpk(float lo, float hi) {
  unsigned r;
  asm("v_cvt_pk_bf16_f32 %0, %1, %2" : "=v"(r) : "v"(lo), "v"(hi));
  return r;
}
__device__ __forceinline__ float fexp2(float x) {
  float r;
  asm("v_exp_f32 %0, %1" : "=v"(r) : "v"(x));
  return r;
}
__device__ __forceinline__ float max3f(float a, float b, float c) {
  return fmaxf(fmaxf(a, b), c);  // clang fuses to v_max3_f32
}
__device__ __forceinline__ void gload_lds16(const void* g, void* l) {
  __builtin_amdgcn_global_load_lds(
      (const __attribute__((address_space(1))) unsigned*)g,
      (__attribute__((address_space(3))) unsigned*)l, 16, 0, 0);
}
__device__ __forceinline__ f32x4 mfma16(bf16x8 a, bf16x8 b, f32x4 c) {
  return __builtin_amdgcn_mfma_f32_16x16x32_bf16(a, b, c, 0, 0, 0);
}

// ---------------- fp32 -> bf16 convert ----------------
__global__ __launch_bounds__(256) void k_cvt(const float* __restrict__ src,
                                             unsigned short* __restrict__ dst, int n4) {
  int i = blockIdx.x * 256 + threadIdx.x;
  if (i >= n4) return;
  float4 v = ((const float4*)src)[i];
  ushort4 o;
  o.x = f2b(v.x); o.y = f2b(v.y); o.z = f2b(v.z); o.w = f2b(v.w);
  ((ushort4*)dst)[i] = o;
}

// ---------------- 1536x1536 transpose fp32 -> bf16 (x3 batched) ----------------
__global__ __launch_bounds__(256) void k_transpose3(const float* __restrict__ s0,
                                                    const float* __restrict__ s1,
                                                    const float* __restrict__ s2,
                                                    unsigned short* __restrict__ dst) {
  __shared__ float tile[64][65];
  const int which = blockIdx.x / 576;
  const int bid = blockIdx.x % 576;
  const float* src = which == 0 ? s0 : (which == 1 ? s1 : s2);
  unsigned short* d = dst + (size_t)which * 1536 * 1536;
  const int tx = threadIdx.x & 63, ty = threadIdx.x >> 6;
  const int r0 = (bid / 24) * 64, c0 = (bid % 24) * 64;
#pragma unroll
  for (int j = 0; j < 16; ++j)
    tile[ty + j * 4][tx] = src[(size_t)(r0 + ty + j * 4) * 1536 + c0 + tx];
  __syncthreads();
#pragma unroll
  for (int j = 0; j < 16; ++j)
    d[(size_t)(c0 + ty + j * 4) * 1536 + r0 + tx] = f2b(tile[tx][ty + j * 4]);
}

__global__ __launch_bounds__(256) void k_transpose(const float* __restrict__ src,
                                                   unsigned short* __restrict__ dst) {
  __shared__ float tile[64][65];
  const int tx = threadIdx.x & 63, ty = threadIdx.x >> 6;
  const int r0 = (blockIdx.x / 24) * 64, c0 = (blockIdx.x % 24) * 64;
#pragma unroll
  for (int j = 0; j < 16; ++j)
    tile[ty + j * 4][tx] = src[(size_t)(r0 + ty + j * 4) * 1536 + c0 + tx];
  __syncthreads();
#pragma unroll
  for (int j = 0; j < 16; ++j)
    dst[(size_t)(c0 + ty + j * 4) * 1536 + r0 + tx] = f2b(tile[tx][ty + j * 4]);
}

// ---------------- m201-style 8-phase 256x256 bf16 GEMM, BK=64, 128KB dyn LDS ----------
// Split-strip mode (nMain=256): blocks [0,256) = main tiles over N in [0,4096),
// full K, bf16 out. Blocks [256,384) = 32 strip tiles (N in [4096,4608)) x 4
// K-slices (K=384 each, NT=6); f32 partials to scratch slot s=tile*4+slice.
// Fallback (nMain=288): original single-grid behavior, no strip.
__global__ __launch_bounds__(512, 2) void k_gemm8(const unsigned short* __restrict__ A,
                                                  const unsigned short* __restrict__ BT,
                                                  unsigned short* __restrict__ C,
                                                  float* __restrict__ scratch,
                                                  int K, int gridNmain, int nMain) {
  extern __shared__ unsigned short lds[];
  unsigned short* As = lds;           // 4 slots x 8192 elems (16KB)
  unsigned short* Bs = lds + 32768;
  const int tid = threadIdx.x;
  const int lane = tid & 63, wave = tid >> 6;
  const int wm = wave >> 2, wn = wave & 3;
  const int r15 = lane & 15, g = lane >> 4;
  const int sw = r15 & 7;

  int bm, bn, kbeg, NT, slot;
  bool partial;
  if ((int)blockIdx.x < nMain) {
    int bid = blockIdx.x;
    int cpx = nMain >> 3;  // bijective XCD swizzle (nMain % 8 == 0)
    bid = (bid & 7) * cpx + (bid >> 3);
    bm = (bid / gridNmain) * 256;
    bn = (bid % gridNmain) * 256;
    kbeg = 0; NT = K >> 6; partial = false; slot = 0;
  } else {
    int s = blockIdx.x - nMain;       // [0,128)
    int tile = s >> 2, slice = s & 3;
    bm = (tile & 15) * 256;
    bn = 4096 + (tile >> 4) * 256;
    kbeg = slice * 384; NT = 6; partial = true; slot = s;
  }
  const unsigned short* Ab = A + kbeg;
  const unsigned short* BTb = BT + kbeg;

  f32x4 acc[8][4] = {};

  auto STAGE = [&](int tl, int part) {
    const bool isB = part >= 2;
    const int half = part & 1;
    const unsigned short* src = isB ? BTb : Ab;
    const int rb = (isB ? bn : bm) + half * 128;
    char* slotp = (char*)(isB ? Bs : As) + ((tl & 1) * 2 + half) * 16384;
#pragma unroll
    for (int i = 0; i < 2; ++i) {
      int cid = i * 512 + tid;
      int row = cid >> 3;
      int logc = (cid & 7) ^ (row & 7);
      gload_lds16(src + (size_t)(rb + row) * K + tl * 64 + logc * 8,
                  slotp + i * 8192 + wave * 1024);
    }
  };

  STAGE(0, 2); STAGE(0, 3); STAGE(0, 0); STAGE(0, 1);
  STAGE(1, 2); STAGE(1, 3); STAGE(1, 0);
  asm volatile("s_waitcnt vmcnt(6)" ::: "memory");
  __builtin_amdgcn_s_barrier();

  bf16x8 af[4][2], bf[4][2];
  for (int t = 0; t < NT; ++t) {
    const int d = t & 1;
    const unsigned short* Aslot = As + (d * 2 + wm) * 8192;
    const unsigned short* Bslot = Bs + (d * 2 + (wn >> 1)) * 8192;
    const int bro = (wn & 1) * 64;

#pragma unroll
    for (int j = 0; j < 4; ++j) {
      const unsigned short* ar = Aslot + (j * 16 + r15) * 64;
      af[j][0] = *(const bf16x8*)(ar + ((g ^ sw) * 8));
      af[j][1] = *(const bf16x8*)(ar + (((4 + g) ^ sw) * 8));
    }
#pragma unroll
    for (int n = 0; n < 2; ++n) {
      const unsigned short* br = Bslot + (bro + n * 16 + r15) * 64;
      bf[n][0] = *(const bf16x8*)(br + ((g ^ sw) * 8));
      bf[n][1] = *(const bf16x8*)(br + (((4 + g) ^ sw) * 8));
    }
    if (t + 1 < NT) STAGE(t + 1, 1);
    __builtin_amdgcn_s_barrier();
    asm volatile("s_waitcnt lgkmcnt(0)" ::: "memory");
    __builtin_amdgcn_sched_barrier(0);
    __builtin_amdgcn_s_setprio(1);
#pragma unroll
    for (int j = 0; j < 4; ++j)
#pragma unroll
      for (int n = 0; n < 2; ++n) {
        acc[j][n] = mfma16(af[j][0], bf[n][0], acc[j][n]);
        acc[j][n] = mfma16(af[j][1], bf[n][1], acc[j][n]);
      }
    __builtin_amdgcn_s_setprio(0);
    __builtin_amdgcn_s_barrier();

#pragma unroll
    for (int n = 2; n < 4; ++n) {
      const unsigned short* br = Bslot + (bro + n * 16 + r15) * 64;
      bf[n][0] = *(const bf16x8*)(br + ((g ^ sw) * 8));
      bf[n][1] = *(const bf16x8*)(br + (((4 + g) ^ sw) * 8));
    }
    __builtin_amdgcn_s_barrier();
    asm volatile("s_waitcnt lgkmcnt(0)" ::: "memory");
    __builtin_amdgcn_sched_barrier(0);
    __builtin_amdgcn_s_setprio(1);
#pragma unroll
    for (int j = 0; j < 4; ++j)
#pragma unroll
      for (int n = 2; n < 4; ++n) {
        acc[j][n] = mfma16(af[j][0], bf[n][0], acc[j][n]);
        acc[j][n] = mfma16(af[j][1], bf[n][1], acc[j][n]);
      }
    __builtin_amdgcn_s_setprio(0);
    __builtin_amdgcn_s_barrier();

#pragma unroll
    for (int j = 0; j < 4; ++j) {
      const unsigned short* ar = Aslot + (64 + j * 16 + r15) * 64;
      af[j][0] = *(const bf16x8*)(ar + ((g ^ sw) * 8));
      af[j][1] = *(const bf16x8*)(ar + (((4 + g) ^ sw) * 8));
    }
    if (t + 2 < NT) STAGE(t + 2, 2);
    __builtin_amdgcn_s_barrier();
    asm volatile("s_waitcnt lgkmcnt(0)" ::: "memory");
    __builtin_amdgcn_sched_barrier(0);
    __builtin_amdgcn_s_setprio(1);
#pragma unroll
    for (int j = 0; j < 4; ++j)
#pragma unroll
      for (int n = 0; n < 2; ++n) {
        acc[4 + j][n] = mfma16(af[j][0], bf[n][0], acc[4 + j][n]);
        acc[4 + j][n] = mfma16(af[j][1], bf[n][1], acc[4 + j][n]);
      }
    __builtin_amdgcn_s_setprio(0);
    __builtin_amdgcn_s_barrier();

    if (t + 2 < NT) { STAGE(t + 2, 3); STAGE(t + 2, 0); }
    __builtin_amdgcn_s_barrier();
    __builtin_amdgcn_s_setprio(1);
#pragma unroll
    for (int j = 0; j < 4; ++j)
#pragma unroll
      for (int n = 2; n < 4; ++n) {
        acc[4 + j][n] = mfma16(af[j][0], bf[n][0], acc[4 + j][n]);
        acc[4 + j][n] = mfma16(af[j][1], bf[n][1], acc[4 + j][n]);
      }
    __builtin_amdgcn_s_setprio(0);
    if (t < NT - 2)
      asm volatile("s_waitcnt vmcnt(6)" ::: "memory");
    else
      asm volatile("s_waitcnt vmcnt(0)" ::: "memory");
    __builtin_amdgcn_s_barrier();
  }

  // epilogue
  if (!partial) {
#pragma unroll
    for (int m = 0; m < 8; ++m)
#pragma unroll
      for (int n = 0; n < 4; ++n)
#pragma unroll
        for (int i = 0; i < 4; ++i) {
          int row = bm + wm * 128 + m * 16 + g * 4 + i;
          int col = bn + wn * 64 + n * 16 + r15;
          C[(size_t)row * 4608 + col] = f2b(acc[m][n][i]);
        }
  } else {
    float* sp = scratch + (size_t)slot * 65536;
#pragma unroll
    for (int m = 0; m < 8; ++m)
#pragma unroll
      for (int n = 0; n < 4; ++n)
#pragma unroll
        for (int i = 0; i < 4; ++i) {
          int rl = wm * 128 + m * 16 + g * 4 + i;
          int cl = wn * 64 + n * 16 + r15;
          sp[rl * 256 + cl] = acc[m][n][i];
        }
  }
}

// ---------------- strip fixup: sum 4 f32 K-slices -> bf16 into qkv ----------------
__global__ __launch_bounds__(256) void k_fixup(const float* __restrict__ scratch,
                                               unsigned short* __restrict__ qkv) {
  size_t gid = (size_t)blockIdx.x * 256 + threadIdx.x;  // 524288 threads x 4 elems
  int tile = (int)(gid >> 14);
  int elem = (int)(gid & 16383) * 4;
  const float* base = scratch + (size_t)tile * 4 * 65536;
  float4 p0 = *(const float4*)(base + elem);
  float4 p1 = *(const float4*)(base + 65536 + elem);
  float4 p2 = *(const float4*)(base + 131072 + elem);
  float4 p3 = *(const float4*)(base + 196608 + elem);
  ushort4 o;
  o.x = f2b(p0.x + p1.x + p2.x + p3.x);
  o.y = f2b(p0.y + p1.y + p2.y + p3.y);
  o.z = f2b(p0.z + p1.z + p2.z + p3.z);
  o.w = f2b(p0.w + p1.w + p2.w + p3.w);
  int r = elem >> 8, c = elem & 255;
  int row = (tile & 15) * 256 + r;
  int col = 4096 + (tile >> 4) * 256 + c;
  *(ushort4*)&qkv[(size_t)row * 4608 + col] = o;
}

// ---------------- bf16 GEMM (m97 pattern) for the output projection ----------------
template <int OUTBF16>
__global__ __launch_bounds__(256) void k_gemm(const unsigned short* __restrict__ A,
                                              const unsigned short* __restrict__ BT,
                                              void* __restrict__ C,
                                              const float* __restrict__ bias,
                                              int M, int N, int K, int gridN) {
  __shared__ unsigned short As[128 * 32];
  __shared__ unsigned short Bs[128 * 32];
  const int tid = threadIdx.x;
  const int lane = tid & 63, wave = tid >> 6;
  int bidx = blockIdx.x;
  {  // bijective XCD swizzle (grid % 8 == 0)
    int cpx = gridDim.x >> 3;
    bidx = (bidx & 7) * cpx + (bidx >> 3);
  }
  const int bm = (bidx / gridN) * 128;
  const int bn = (bidx % gridN) * 128;
  const int wr = (wave >> 1) * 64, wc = (wave & 1) * 64;
  const int r15 = lane & 15, g = lane >> 4;
  const int row0 = tid >> 2, c0 = tid & 3;

  f32x4 acc[4][4] = {};

  for (int k0 = 0; k0 < K; k0 += 32) {
    __syncthreads();
    gload_lds16(A + (size_t)(bm + row0) * K + k0 + c0 * 8, (char*)As + wave * 1024);
    gload_lds16(A + (size_t)(bm + row0 + 64) * K + k0 + c0 * 8,
                (char*)As + 4096 + wave * 1024);
    gload_lds16(BT + (size_t)(bn + row0) * K + k0 + c0 * 8, (char*)Bs + wave * 1024);
    gload_lds16(BT + (size_t)(bn + row0 + 64) * K + k0 + c0 * 8,
                (char*)Bs + 4096 + wave * 1024);
    __syncthreads();
    bf16x8 af[4], bfr[4];
#pragma unroll
    for (int m = 0; m < 4; ++m) {
      af[m] = *(const bf16x8*)&As[(wr + m * 16 + r15) * 32 + g * 8];
      bfr[m] = *(const bf16x8*)&Bs[(wc + m * 16 + r15) * 32 + g * 8];
    }
#pragma unroll
    for (int m = 0; m < 4; ++m)
#pragma unroll
      for (int n = 0; n < 4; ++n)
        acc[m][n] = mfma16(af[m], bfr[n], acc[m][n]);
  }

#pragma unroll
  for (int m = 0; m < 4; ++m)
#pragma unroll
    for (int n = 0; n < 4; ++n)
#pragma unroll
      for (int i = 0; i < 4; ++i) {
        int row = bm + wr + m * 16 + g * 4 + i;
        int col = bn + wc + n * 16 + r15;
        float v = acc[m][n][i];
        if (OUTBF16)
          ((unsigned short*)C)[(size_t)row * N + col] = f2b(v);
        else
          ((float*)C)[(size_t)row * N + col] = v + bias[col];
      }
}

// ---------------- K/V low-rank injection (RMW on bf16 K,V) ----------------
__global__ __launch_bounds__(256) void k_inject(const float* __restrict__ Mm,
                                                const float* __restrict__ Wr,
                                                const float* __restrict__ Fk,
                                                const float* __restrict__ Fv,
                                                unsigned short* __restrict__ qkv) {
  __shared__ float Ml[256];
  __shared__ float gl[4];
  const int bid = blockIdx.x;  // 4096 = B(2)*H(8)*T(4)*NB(64)
  const int nb = bid & 63, t = (bid >> 6) & 3, h = (bid >> 8) & 7, b = bid >> 11;
  const int tid = threadIdx.x;
  const int nl = tid >> 6, d = tid & 63;
  Ml[tid] = Mm[(size_t)(((b * 4 + t) * 256 + nb * 4) * 64) + tid];
  if (tid < 4) gl[tid] = Wr[(b * 4 + t) * 256 + nb * 4 + tid];
  __syncthreads();
  float ak = 0.f, av = 0.f;
#pragma unroll 8
  for (int f = 0; f < 64; ++f) {
    float mv = Ml[nl * 64 + f];
    ak += mv * Fk[(h * 64 + f) * 64 + d];
    av += mv * Fv[(h * 64 + f) * 64 + d];
  }
  float gate = gl[nl];
  ak *= gate; av *= gate;
  const int n = nb * 4 + nl;
  const size_t s0 = (size_t)(b * 2048 + t * 256 + n);
#pragma unroll
  for (int r = 0; r < 2; ++r) {
    size_t row = s0 + (size_t)r * 1024;
    size_t ik = row * 4608 + 1536 + h * 64 + d;
    qkv[ik] = f2b(b2f(qkv[ik]) + ak);
    size_t iv = row * 4608 + 3072 + h * 64 + d;
    qkv[iv] = f2b(b2f(qkv[iv]) + av);
  }
}

// ---------------- flash attention, swapped QK^T, P-in-register ----------------
// Round-13 base + (1) l via MFMA-with-ones (l_acc rides o's rescale; epilogue
// needs no shuffle), (2) v_max3 max tree, (3) VT row stride 72 -> 76 (V-read
// bank dispersion: (6*r15+4g) mod 32 all-distinct in r15 -> ~2-way, free).
__global__ __launch_bounds__(256, 3) void k_attn(const unsigned short* __restrict__ qkv,
                                                 unsigned short* __restrict__ attno) {
  __shared__ unsigned short Kl[2 * 64 * 64];   // 16 KB
  __shared__ unsigned short VT[2 * 64 * 76];   // 19 KB
  const int tid = threadIdx.x;
  const int lane = tid & 63, wave = tid >> 6;
  const int bid = blockIdx.x;  // 768 = B*24*16
  const int qt = bid & 15;
  const int h = (bid >> 4) % 24;
  const int b = (bid >> 4) / 24;
  const int r15 = lane & 15, g = lane >> 4;
  const int q0 = qt * 128 + wave * 32;
  const size_t RS = 4608;
  const size_t tokbase = (size_t)(b * 2048);
  const int VSTR = 76, VTSZ = 64 * 76;

  bf16x8 qb[2][2];
  {
    const float qs = 0.125f * LOG2E;
#pragma unroll
    for (int qh = 0; qh < 2; ++qh) {
      const unsigned short* qrow = qkv + (tokbase + q0 + qh * 16 + r15) * RS + h * 64;
#pragma unroll
      for (int kk = 0; kk < 2; ++kk) {
        bf16x8 v = *(const bf16x8*)(qrow + kk * 32 + g * 8);
#pragma unroll
        for (int e = 0; e < 8; ++e)
          v[e] = (short)f2b(b2f((unsigned short)v[e]) * qs);
        qb[qh][kk] = v;
      }
    }
  }
  bf16x8 ones;
#pragma unroll
  for (int e = 0; e < 8; ++e) ones[e] = (short)0x3F80;  // bf16 1.0

  f32x4 o[2][4] = {};
  f32x4 l_acc[2] = {};
  float m_run[2] = {-1e30f, -1e30f};
  bf16x8 vr[2];

  const int ch0 = wave * 2 * 64 + lane, ch1 = (wave * 2 + 1) * 64 + lane;
  const int kr0 = ch0 >> 3, kc0s = ((ch0 & 7) ^ (kr0 & 7)) * 8;
  const int kr1 = ch1 >> 3, kc1s = ((ch1 & 7) ^ (kr1 & 7)) * 8;
  // V staging column: k'(kv=lane) = (kv>>5)*32 + ((kv>>2)&3)*8 + ((kv>>4)&1)*4 + (kv&3)
  const int kcol = ((lane >> 5) & 1) * 32 + ((lane >> 2) & 3) * 8 +
                   ((lane >> 4) & 1) * 4 + (lane & 3);

#define STAGE_K(buf, kv0)                                                          \
  {                                                                                \
    gload_lds16(qkv + (tokbase + (kv0) + kr0) * RS + 1536 + h * 64 + kc0s,         \
                (char*)Kl + (buf) * 8192 + (wave * 2) * 1024);                     \
    gload_lds16(qkv + (tokbase + (kv0) + kr1) * RS + 1536 + h * 64 + kc1s,         \
                (char*)Kl + (buf) * 8192 + (wave * 2 + 1) * 1024);                 \
  }
#define LOAD_V(kv0)                                                                \
  {                                                                                \
    const unsigned short* vrow = qkv + (tokbase + (kv0) + lane) * RS + 3072 + h * 64; \
    vr[0] = *(const bf16x8*)(vrow + (wave * 2) * 8);                               \
    vr[1] = *(const bf16x8*)(vrow + (wave * 2 + 1) * 8);                           \
  }
#define WRITE_V(buf)                                                               \
  {                                                                                \
    _Pragma("unroll") for (int s = 0; s < 2; ++s) {                                \
      int d0 = (wave * 2 + s) * 8;                                                 \
      _Pragma("unroll") for (int e = 0; e < 8; ++e)                                \
          VT[(buf) * VTSZ + (d0 + e) * VSTR + kcol] = (unsigned short)vr[s][e];    \
    }                                                                              \
  }

  STAGE_K(0, 0);
  LOAD_V(0);
  asm volatile("s_waitcnt vmcnt(0)" ::: "memory");
  WRITE_V(0);
  __syncthreads();

  int cur = 0;
  for (int t = 0; t < 32; ++t) {
    const int kv0 = t * 64;
    if (t < 31) {
      STAGE_K(cur ^ 1, kv0 + 64);
      LOAD_V(kv0 + 64);
    }

    f32x4 st[4][2];
    const unsigned short* Kb = Kl + cur * 4096;
    __builtin_amdgcn_s_setprio(1);
#pragma unroll
    for (int m = 0; m < 4; ++m) {
      int row = m * 16 + r15;
      int r7 = row & 7;
      bf16x8 ka0 = *(const bf16x8*)&Kb[row * 64 + ((g ^ r7) * 8)];
      bf16x8 ka1 = *(const bf16x8*)&Kb[row * 64 + (((4 + g) ^ r7) * 8)];
#pragma unroll
      for (int qh = 0; qh < 2; ++qh) {
        f32x4 z = {0.f, 0.f, 0.f, 0.f};
        st[m][qh] = mfma16(ka0, qb[qh][0], z);
        st[m][qh] = mfma16(ka1, qb[qh][1], st[m][qh]);
      }
    }
    __builtin_amdgcn_s_setprio(0);

    float pm[2];
#pragma unroll
    for (int qh = 0; qh < 2; ++qh) {
      float t0 = max3f(st[0][qh][0], st[0][qh][1], st[0][qh][2]);
      float t1 = max3f(st[0][qh][3], st[1][qh][0], st[1][qh][1]);
      float t2 = max3f(st[1][qh][2], st[1][qh][3], st[2][qh][0]);
      float t3 = max3f(st[2][qh][1], st[2][qh][2], st[2][qh][3]);
      float t4 = max3f(st[3][qh][0], st[3][qh][1], st[3][qh][2]);
      float p = fmaxf(max3f(t0, t1, t2), max3f(t3, t4, st[3][qh][3]));
      p = fmaxf(p, __shfl_xor(p, 16, 64));
      pm[qh] = fmaxf(p, __shfl_xor(p, 32, 64));
    }

    if (!__all(pm[0] - m_run[0] <= 8.0f && pm[1] - m_run[1] <= 8.0f)) {
#pragma unroll
      for (int qh = 0; qh < 2; ++qh) {
        float mnew = fmaxf(m_run[qh], pm[qh]);
        float fac = fexp2(m_run[qh] - mnew);
        float f_i[4];
#pragma unroll
        for (int i = 0; i < 4; ++i)
          f_i[i] = __shfl(fac, (lane & 48) | ((((lane >> 4) & 3) << 2) + i), 64);
#pragma unroll
        for (int dt = 0; dt < 4; ++dt)
#pragma unroll
          for (int i = 0; i < 4; ++i) o[qh][dt][i] *= f_i[i];
#pragma unroll
        for (int i = 0; i < 4; ++i) l_acc[qh][i] *= f_i[i];
        m_run[qh] = mnew;
      }
    }

    // P = 2^(st - m); pack to bf16 pairs, kept in registers
    unsigned pku[2][4][2];
#pragma unroll
    for (int m = 0; m < 4; ++m)
#pragma unroll
      for (int qh = 0; qh < 2; ++qh) {
        float p0 = fexp2(st[m][qh][0] - m_run[qh]);
        float p1 = fexp2(st[m][qh][1] - m_run[qh]);
        float p2 = fexp2(st[m][qh][2] - m_run[qh]);
        float p3 = fexp2(st[m][qh][3] - m_run[qh]);
        pku[qh][m][0] = cvtpk(p0, p1);
        pku[qh][m][1] = cvtpk(p2, p3);
      }

    // PV with permuted kv; l accumulated via MFMA with all-ones B fragment
    const unsigned short* Vb = VT + cur * VTSZ;
    __builtin_amdgcn_s_setprio(1);
#pragma unroll
    for (int kap = 0; kap < 2; ++kap) {
      union { bf16x8 v; unsigned u[4]; } pa0, pa1;
      pa0.u[0] = pku[0][2 * kap][0];     pa0.u[1] = pku[0][2 * kap][1];
      pa0.u[2] = pku[0][2 * kap + 1][0]; pa0.u[3] = pku[0][2 * kap + 1][1];
      pa1.u[0] = pku[1][2 * kap][0];     pa1.u[1] = pku[1][2 * kap][1];
      pa1.u[2] = pku[1][2 * kap + 1][0]; pa1.u[3] = pku[1][2 * kap + 1][1];
#pragma unroll
      for (int dt = 0; dt < 4; ++dt) {
        bf16x8 vb = *(const bf16x8*)&Vb[(dt * 16 + r15) * VSTR + kap * 32 + g * 8];
        o[0][dt] = mfma16(pa0.v, vb, o[0][dt]);
        o[1][dt] = mfma16(pa1.v, vb, o[1][dt]);
      }
      l_acc[0] = mfma16(pa0.v, ones, l_acc[0]);
      l_acc[1] = mfma16(pa1.v, ones, l_acc[1]);
    }
    __builtin_amdgcn_s_setprio(0);

    if (t < 31) {
      asm volatile("s_waitcnt vmcnt(0)" ::: "memory");
      WRITE_V(cur ^ 1);
    }
    __syncthreads();
    cur ^= 1;
  }

  // epilogue: l_acc[qh][i] is l for this lane's own q-row (q = 4g+i) - no shuffle
#pragma unroll
  for (int qh = 0; qh < 2; ++qh) {
    float r_i[4];
#pragma unroll
    for (int i = 0; i < 4; ++i) r_i[i] = 1.0f / l_acc[qh][i];
#pragma unroll
    for (int dt = 0; dt < 4; ++dt)
#pragma unroll
      for (int i = 0; i < 4; ++i) {
        int q = q0 + qh * 16 + ((lane >> 4) << 2) + i;
        int col = h * 64 + dt * 16 + r15;
        attno[(tokbase + q) * 1536 + col] = f2b(o[qh][dt][i] * r_i[i]);
      }
  }
}

extern "C" void kernel_launch(void* const* d_in, const int* in_sizes, int n_in,
                              void* d_out, int out_size, void* d_ws, size_t ws_size,
                              hipStream_t stream) {
  const float* hs = (const float*)d_in[0];
  const float* Wq = (const float*)d_in[1];
  const float* Wk = (const float*)d_in[2];
  const float* Wv = (const float*)d_in[3];
  const float* Wo = (const float*)d_in[4];
  const float* bo = (const float*)d_in[5];
  const float* Mm = (const float*)d_in[6];
  const float* Wr = (const float*)d_in[7];
  const float* Fk = (const float*)d_in[8];
  const float* Fv = (const float*)d_in[9];
  float* out = (float*)d_out;

  unsigned short* hsb   = (unsigned short*)d_ws;
  unsigned short* wqkvt = hsb + (size_t)4096 * 1536;
  unsigned short* qkv   = wqkvt + (size_t)4608 * 1536;
  unsigned short* attno = hsb;
  unsigned short* wot   = wqkvt;

  // strip split-K scratch: 128 slots x 65536 f32 = 33.55 MB after the bf16 buffers
  const size_t base_bytes = ((size_t)4096 * 1536 + (size_t)4608 * 1536 +
                             (size_t)4096 * 4608) * 2;  // 64.49 MB
  float* scratch = (float*)((char*)d_ws + base_bytes);
  const bool split = ws_size >= base_bytes + (size_t)128 * 65536 * 4;

  hipFuncSetAttribute((const void*)k_gemm8,
                      hipFuncAttributeMaxDynamicSharedMemorySize, 131072);

  k_cvt<<<6144, 256, 0, stream>>>(hs, hsb, 1572864);
  k_transpose3<<<1728, 256, 0, stream>>>(Wq, Wk, Wv, wqkvt);

  if (split) {
    k_gemm8<<<384, 512, 131072, stream>>>(hsb, wqkvt, qkv, scratch, 1536, 16, 256);
    k_fixup<<<2048, 256, 0, stream>>>(scratch, qkv);
  } else {
    k_gemm8<<<288, 512, 131072, stream>>>(hsb, wqkvt, qkv, (float*)nullptr, 1536, 18, 288);
  }
  k_transpose<<<576, 256, 0, stream>>>(Wo, wot);  // after gemm8: wot aliases wqkvt
  k_inject<<<4096, 256, 0, stream>>>(Mm, Wr, Fk, Fv, qkv);
  k_attn<<<768, 256, 0, stream>>>(qkv, attno);    // attno aliases hsb
  k_gemm<0><<<32 * 12, 256, 0, stream>>>(attno, wot, (void*)out, bo, 4096, 1536, 1536, 12);
}

// Round 15
// 223.245 us; speedup vs baseline: 1.2477x; 1.2477x over previous
//
#include <hip/hip_runtime.h>
#include <hip/hip_bf16.h>

typedef __attribute__((ext_vector_type(4))) float f32x4;
typedef __attribute__((ext_vector_type(8))) short bf16x8;

#define LOG2E 1.4426950408889634f

__device__ __forceinline__ unsigned short f2b(float f) {
  union { float f; unsigned u; } v; v.f = f;
  unsigned r = v.u + 0x7fffu + ((v.u >> 16) & 1u);
  return (unsigned short)(r >> 16);
}
__device__ __forceinline__ float b2f(unsigned short s) {
  union { unsigned u; float f; } v; v.u = ((unsigned)s) << 16;
  return v.f;
}
__device__ __forceinline__ unsigned cvtpk(float lo, float hi) {
  unsigned r;
  asm("v_cvt_pk_bf16_f32 %0, %1, %2" : "=v"(r) : "v"(lo), "v"(hi));
  return r;
}
__device__ __forceinline__ float fexp2(float x) {
  float r;
  asm("v_exp_f32 %0, %1" : "=v"(r) : "v"(x));
  return r;
}
__device__ __forceinline__ float max3f(float a, float b, float c) {
  return fmaxf(fmaxf(a, b), c);  // clang fuses to v_max3_f32
}
__device__ __forceinline__ void gload_lds16(const void* g, void* l) {
  __builtin_amdgcn_global_load_lds(
      (const __attribute__((address_space(1))) unsigned*)g,
      (__attribute__((address_space(3))) unsigned*)l, 16, 0, 0);
}
__device__ __forceinline__ f32x4 mfma16(bf16x8 a, bf16x8 b, f32x4 c) {
  return __builtin_amdgcn_mfma_f32_16x16x32_bf16(a, b, c, 0, 0, 0);
}

// ---------------- fp32 -> bf16 convert ----------------
__global__ __launch_bounds__(256) void k_cvt(const float* __restrict__ src,
                                             unsigned short* __restrict__ dst, int n4) {
  int i = blockIdx.x * 256 + threadIdx.x;
  if (i >= n4) return;
  float4 v = ((const float4*)src)[i];
  ushort4 o;
  o.x = f2b(v.x); o.y = f2b(v.y); o.z = f2b(v.z); o.w = f2b(v.w);
  ((ushort4*)dst)[i] = o;
}

// ---------------- 1536x1536 transpose fp32 -> bf16 (x3 batched) ----------------
__global__ __launch_bounds__(256) void k_transpose3(const float* __restrict__ s0,
                                                    const float* __restrict__ s1,
                                                    const float* __restrict__ s2,
                                                    unsigned short* __restrict__ dst) {
  __shared__ float tile[64][65];
  const int which = blockIdx.x / 576;
  const int bid = blockIdx.x % 576;
  const float* src = which == 0 ? s0 : (which == 1 ? s1 : s2);
  unsigned short* d = dst + (size_t)which * 1536 * 1536;
  const int tx = threadIdx.x & 63, ty = threadIdx.x >> 6;
  const int r0 = (bid / 24) * 64, c0 = (bid % 24) * 64;
#pragma unroll
  for (int j = 0; j < 16; ++j)
    tile[ty + j * 4][tx] = src[(size_t)(r0 + ty + j * 4) * 1536 + c0 + tx];
  __syncthreads();
#pragma unroll
  for (int j = 0; j < 16; ++j)
    d[(size_t)(c0 + ty + j * 4) * 1536 + r0 + tx] = f2b(tile[tx][ty + j * 4]);
}

__global__ __launch_bounds__(256) void k_transpose(const float* __restrict__ src,
                                                   unsigned short* __restrict__ dst) {
  __shared__ float tile[64][65];
  const int tx = threadIdx.x & 63, ty = threadIdx.x >> 6;
  const int r0 = (blockIdx.x / 24) * 64, c0 = (blockIdx.x % 24) * 64;
#pragma unroll
  for (int j = 0; j < 16; ++j)
    tile[ty + j * 4][tx] = src[(size_t)(r0 + ty + j * 4) * 1536 + c0 + tx];
  __syncthreads();
#pragma unroll
  for (int j = 0; j < 16; ++j)
    dst[(size_t)(c0 + ty + j * 4) * 1536 + r0 + tx] = f2b(tile[tx][ty + j * 4]);
}

// ---------------- m201-style 8-phase 256x256 bf16 GEMM, BK=64, 128KB dyn LDS ----------
// Split-strip mode (nMain=256): blocks [0,256) = main tiles over N in [0,4096),
// full K, bf16 out. Blocks [256,384) = 32 strip tiles (N in [4096,4608)) x 4
// K-slices (K=384 each, NT=6); f32 partials to scratch slot s=tile*4+slice.
// Fallback (nMain=288): original single-grid behavior, no strip.
__global__ __launch_bounds__(512, 2) void k_gemm8(const unsigned short* __restrict__ A,
                                                  const unsigned short* __restrict__ BT,
                                                  unsigned short* __restrict__ C,
                                                  float* __restrict__ scratch,
                                                  int K, int gridNmain, int nMain) {
  extern __shared__ unsigned short lds[];
  unsigned short* As = lds;           // 4 slots x 8192 elems (16KB)
  unsigned short* Bs = lds + 32768;
  const int tid = threadIdx.x;
  const int lane = tid & 63, wave = tid >> 6;
  const int wm = wave >> 2, wn = wave & 3;
  const int r15 = lane & 15, g = lane >> 4;
  const int sw = r15 & 7;

  int bm, bn, kbeg, NT, slot;
  bool partial;
  if ((int)blockIdx.x < nMain) {
    int bid = blockIdx.x;
    int cpx = nMain >> 3;  // bijective XCD swizzle (nMain % 8 == 0)
    bid = (bid & 7) * cpx + (bid >> 3);
    bm = (bid / gridNmain) * 256;
    bn = (bid % gridNmain) * 256;
    kbeg = 0; NT = K >> 6; partial = false; slot = 0;
  } else {
    int s = blockIdx.x - nMain;       // [0,128)
    int tile = s >> 2, slice = s & 3;
    bm = (tile & 15) * 256;
    bn = 4096 + (tile >> 4) * 256;
    kbeg = slice * 384; NT = 6; partial = true; slot = s;
  }
  const unsigned short* Ab = A + kbeg;
  const unsigned short* BTb = BT + kbeg;

  f32x4 acc[8][4] = {};

  auto STAGE = [&](int tl, int part) {
    const bool isB = part >= 2;
    const int half = part & 1;
    const unsigned short* src = isB ? BTb : Ab;
    const int rb = (isB ? bn : bm) + half * 128;
    char* slotp = (char*)(isB ? Bs : As) + ((tl & 1) * 2 + half) * 16384;
#pragma unroll
    for (int i = 0; i < 2; ++i) {
      int cid = i * 512 + tid;
      int row = cid >> 3;
      int logc = (cid & 7) ^ (row & 7);
      gload_lds16(src + (size_t)(rb + row) * K + tl * 64 + logc * 8,
                  slotp + i * 8192 + wave * 1024);
    }
  };

  STAGE(0, 2); STAGE(0, 3); STAGE(0, 0); STAGE(0, 1);
  STAGE(1, 2); STAGE(1, 3); STAGE(1, 0);
  asm volatile("s_waitcnt vmcnt(6)" ::: "memory");
  __builtin_amdgcn_s_barrier();

  bf16x8 af[4][2], bf[4][2];
  for (int t = 0; t < NT; ++t) {
    const int d = t & 1;
    const unsigned short* Aslot = As + (d * 2 + wm) * 8192;
    const unsigned short* Bslot = Bs + (d * 2 + (wn >> 1)) * 8192;
    const int bro = (wn & 1) * 64;

#pragma unroll
    for (int j = 0; j < 4; ++j) {
      const unsigned short* ar = Aslot + (j * 16 + r15) * 64;
      af[j][0] = *(const bf16x8*)(ar + ((g ^ sw) * 8));
      af[j][1] = *(const bf16x8*)(ar + (((4 + g) ^ sw) * 8));
    }
#pragma unroll
    for (int n = 0; n < 2; ++n) {
      const unsigned short* br = Bslot + (bro + n * 16 + r15) * 64;
      bf[n][0] = *(const bf16x8*)(br + ((g ^ sw) * 8));
      bf[n][1] = *(const bf16x8*)(br + (((4 + g) ^ sw) * 8));
    }
    if (t + 1 < NT) STAGE(t + 1, 1);
    __builtin_amdgcn_s_barrier();
    asm volatile("s_waitcnt lgkmcnt(0)" ::: "memory");
    __builtin_amdgcn_sched_barrier(0);
    __builtin_amdgcn_s_setprio(1);
#pragma unroll
    for (int j = 0; j < 4; ++j)
#pragma unroll
      for (int n = 0; n < 2; ++n) {
        acc[j][n] = mfma16(af[j][0], bf[n][0], acc[j][n]);
        acc[j][n] = mfma16(af[j][1], bf[n][1], acc[j][n]);
      }
    __builtin_amdgcn_s_setprio(0);
    __builtin_amdgcn_s_barrier();

#pragma unroll
    for (int n = 2; n < 4; ++n) {
      const unsigned short* br = Bslot + (bro + n * 16 + r15) * 64;
      bf[n][0] = *(const bf16x8*)(br + ((g ^ sw) * 8));
      bf[n][1] = *(const bf16x8*)(br + (((4 + g) ^ sw) * 8));
    }
    __builtin_amdgcn_s_barrier();
    asm volatile("s_waitcnt lgkmcnt(0)" ::: "memory");
    __builtin_amdgcn_sched_barrier(0);
    __builtin_amdgcn_s_setprio(1);
#pragma unroll
    for (int j = 0; j < 4; ++j)
#pragma unroll
      for (int n = 2; n < 4; ++n) {
        acc[j][n] = mfma16(af[j][0], bf[n][0], acc[j][n]);
        acc[j][n] = mfma16(af[j][1], bf[n][1], acc[j][n]);
      }
    __builtin_amdgcn_s_setprio(0);
    __builtin_amdgcn_s_barrier();

#pragma unroll
    for (int j = 0; j < 4; ++j) {
      const unsigned short* ar = Aslot + (64 + j * 16 + r15) * 64;
      af[j][0] = *(const bf16x8*)(ar + ((g ^ sw) * 8));
      af[j][1] = *(const bf16x8*)(ar + (((4 + g) ^ sw) * 8));
    }
    if (t + 2 < NT) STAGE(t + 2, 2);
    __builtin_amdgcn_s_barrier();
    asm volatile("s_waitcnt lgkmcnt(0)" ::: "memory");
    __builtin_amdgcn_sched_barrier(0);
    __builtin_amdgcn_s_setprio(1);
#pragma unroll
    for (int j = 0; j < 4; ++j)
#pragma unroll
      for (int n = 0; n < 2; ++n) {
        acc[4 + j][n] = mfma16(af[j][0], bf[n][0], acc[4 + j][n]);
        acc[4 + j][n] = mfma16(af[j][1], bf[n][1], acc[4 + j][n]);
      }
    __builtin_amdgcn_s_setprio(0);
    __builtin_amdgcn_s_barrier();

    if (t + 2 < NT) { STAGE(t + 2, 3); STAGE(t + 2, 0); }
    __builtin_amdgcn_s_barrier();
    __builtin_amdgcn_s_setprio(1);
#pragma unroll
    for (int j = 0; j < 4; ++j)
#pragma unroll
      for (int n = 2; n < 4; ++n) {
        acc[4 + j][n] = mfma16(af[j][0], bf[n][0], acc[4 + j][n]);
        acc[4 + j][n] = mfma16(af[j][1], bf[n][1], acc[4 + j][n]);
      }
    __builtin_amdgcn_s_setprio(0);
    if (t < NT - 2)
      asm volatile("s_waitcnt vmcnt(6)" ::: "memory");
    else
      asm volatile("s_waitcnt vmcnt(0)" ::: "memory");
    __builtin_amdgcn_s_barrier();
  }

  // epilogue
  if (!partial) {
#pragma unroll
    for (int m = 0; m < 8; ++m)
#pragma unroll
      for (int n = 0; n < 4; ++n)
#pragma unroll
        for (int i = 0; i < 4; ++i) {
          int row = bm + wm * 128 + m * 16 + g * 4 + i;
          int col = bn + wn * 64 + n * 16 + r15;
          C[(size_t)row * 4608 + col] = f2b(acc[m][n][i]);
        }
  } else {
    float* sp = scratch + (size_t)slot * 65536;
#pragma unroll
    for (int m = 0; m < 8; ++m)
#pragma unroll
      for (int n = 0; n < 4; ++n)
#pragma unroll
        for (int i = 0; i < 4; ++i) {
          int rl = wm * 128 + m * 16 + g * 4 + i;
          int cl = wn * 64 + n * 16 + r15;
          sp[rl * 256 + cl] = acc[m][n][i];
        }
  }
}

// ---------------- strip fixup: sum 4 f32 K-slices -> bf16 into qkv ----------------
__global__ __launch_bounds__(256) void k_fixup(const float* __restrict__ scratch,
                                               unsigned short* __restrict__ qkv) {
  size_t gid = (size_t)blockIdx.x * 256 + threadIdx.x;  // 524288 threads x 4 elems
  int tile = (int)(gid >> 14);
  int elem = (int)(gid & 16383) * 4;
  const float* base = scratch + (size_t)tile * 4 * 65536;
  float4 p0 = *(const float4*)(base + elem);
  float4 p1 = *(const float4*)(base + 65536 + elem);
  float4 p2 = *(const float4*)(base + 131072 + elem);
  float4 p3 = *(const float4*)(base + 196608 + elem);
  ushort4 o;
  o.x = f2b(p0.x + p1.x + p2.x + p3.x);
  o.y = f2b(p0.y + p1.y + p2.y + p3.y);
  o.z = f2b(p0.z + p1.z + p2.z + p3.z);
  o.w = f2b(p0.w + p1.w + p2.w + p3.w);
  int r = elem >> 8, c = elem & 255;
  int row = (tile & 15) * 256 + r;
  int col = 4096 + (tile >> 4) * 256 + c;
  *(ushort4*)&qkv[(size_t)row * 4608 + col] = o;
}

// ---------------- bf16 GEMM (m97 pattern) for the output projection ----------------
template <int OUTBF16>
__global__ __launch_bounds__(256) void k_gemm(const unsigned short* __restrict__ A,
                                              const unsigned short* __restrict__ BT,
                                              void* __restrict__ C,
                                              const float* __restrict__ bias,
                                              int M, int N, int K, int gridN) {
  __shared__ unsigned short As[128 * 32];
  __shared__ unsigned short Bs[128 * 32];
  const int tid = threadIdx.x;
  const int lane = tid & 63, wave = tid >> 6;
  int bidx = blockIdx.x;
  {  // bijective XCD swizzle (grid % 8 == 0)
    int cpx = gridDim.x >> 3;
    bidx = (bidx & 7) * cpx + (bidx >> 3);
  }
  const int bm = (bidx / gridN) * 128;
  const int bn = (bidx % gridN) * 128;
  const int wr = (wave >> 1) * 64, wc = (wave & 1) * 64;
  const int r15 = lane & 15, g = lane >> 4;
  const int row0 = tid >> 2, c0 = tid & 3;

  f32x4 acc[4][4] = {};

  for (int k0 = 0; k0 < K; k0 += 32) {
    __syncthreads();
    gload_lds16(A + (size_t)(bm + row0) * K + k0 + c0 * 8, (char*)As + wave * 1024);
    gload_lds16(A + (size_t)(bm + row0 + 64) * K + k0 + c0 * 8,
                (char*)As + 4096 + wave * 1024);
    gload_lds16(BT + (size_t)(bn + row0) * K + k0 + c0 * 8, (char*)Bs + wave * 1024);
    gload_lds16(BT + (size_t)(bn + row0 + 64) * K + k0 + c0 * 8,
                (char*)Bs + 4096 + wave * 1024);
    __syncthreads();
    bf16x8 af[4], bfr[4];
#pragma unroll
    for (int m = 0; m < 4; ++m) {
      af[m] = *(const bf16x8*)&As[(wr + m * 16 + r15) * 32 + g * 8];
      bfr[m] = *(const bf16x8*)&Bs[(wc + m * 16 + r15) * 32 + g * 8];
    }
#pragma unroll
    for (int m = 0; m < 4; ++m)
#pragma unroll
      for (int n = 0; n < 4; ++n)
        acc[m][n] = mfma16(af[m], bfr[n], acc[m][n]);
  }

#pragma unroll
  for (int m = 0; m < 4; ++m)
#pragma unroll
    for (int n = 0; n < 4; ++n)
#pragma unroll
      for (int i = 0; i < 4; ++i) {
        int row = bm + wr + m * 16 + g * 4 + i;
        int col = bn + wc + n * 16 + r15;
        float v = acc[m][n][i];
        if (OUTBF16)
          ((unsigned short*)C)[(size_t)row * N + col] = f2b(v);
        else
          ((float*)C)[(size_t)row * N + col] = v + bias[col];
      }
}

// ---------------- K/V low-rank injection (RMW on bf16 K,V) ----------------
__global__ __launch_bounds__(256) void k_inject(const float* __restrict__ Mm,
                                                const float* __restrict__ Wr,
                                                const float* __restrict__ Fk,
                                                const float* __restrict__ Fv,
                                                unsigned short* __restrict__ qkv) {
  __shared__ float Ml[256];
  __shared__ float gl[4];
  const int bid = blockIdx.x;  // 4096 = B(2)*H(8)*T(4)*NB(64)
  const int nb = bid & 63, t = (bid >> 6) & 3, h = (bid >> 8) & 7, b = bid >> 11;
  const int tid = threadIdx.x;
  const int nl = tid >> 6, d = tid & 63;
  Ml[tid] = Mm[(size_t)(((b * 4 + t) * 256 + nb * 4) * 64) + tid];
  if (tid < 4) gl[tid] = Wr[(b * 4 + t) * 256 + nb * 4 + tid];
  __syncthreads();
  float ak = 0.f, av = 0.f;
#pragma unroll 8
  for (int f = 0; f < 64; ++f) {
    float mv = Ml[nl * 64 + f];
    ak += mv * Fk[(h * 64 + f) * 64 + d];
    av += mv * Fv[(h * 64 + f) * 64 + d];
  }
  float gate = gl[nl];
  ak *= gate; av *= gate;
  const int n = nb * 4 + nl;
  const size_t s0 = (size_t)(b * 2048 + t * 256 + n);
#pragma unroll
  for (int r = 0; r < 2; ++r) {
    size_t row = s0 + (size_t)r * 1024;
    size_t ik = row * 4608 + 1536 + h * 64 + d;
    qkv[ik] = f2b(b2f(qkv[ik]) + ak);
    size_t iv = row * 4608 + 3072 + h * 64 + d;
    qkv[iv] = f2b(b2f(qkv[iv]) + av);
  }
}

// ---------------- flash attention, swapped QK^T, P-in-register ----------------
// Round-13 version (benched 87.2us) + ONLY the max3 tree (isolated VALU cut).
__global__ __launch_bounds__(256, 3) void k_attn(const unsigned short* __restrict__ qkv,
                                                 unsigned short* __restrict__ attno) {
  __shared__ unsigned short Kl[2 * 64 * 64];   // 16 KB
  __shared__ unsigned short VT[2 * 64 * 72];   // 18 KB
  const int tid = threadIdx.x;
  const int lane = tid & 63, wave = tid >> 6;
  const int bid = blockIdx.x;  // 768 = B*24*16
  const int qt = bid & 15;
  const int h = (bid >> 4) % 24;
  const int b = (bid >> 4) / 24;
  const int r15 = lane & 15, g = lane >> 4;
  const int q0 = qt * 128 + wave * 32;
  const size_t RS = 4608;
  const size_t tokbase = (size_t)(b * 2048);

  bf16x8 qb[2][2];
  {
    const float qs = 0.125f * LOG2E;
#pragma unroll
    for (int qh = 0; qh < 2; ++qh) {
      const unsigned short* qrow = qkv + (tokbase + q0 + qh * 16 + r15) * RS + h * 64;
#pragma unroll
      for (int kk = 0; kk < 2; ++kk) {
        bf16x8 v = *(const bf16x8*)(qrow + kk * 32 + g * 8);
#pragma unroll
        for (int e = 0; e < 8; ++e)
          v[e] = (short)f2b(b2f((unsigned short)v[e]) * qs);
        qb[qh][kk] = v;
      }
    }
  }

  f32x4 o[2][4] = {};
  float m_run[2] = {-1e30f, -1e30f}, l_run[2] = {0.f, 0.f};
  bf16x8 vr[2];

  const int ch0 = wave * 2 * 64 + lane, ch1 = (wave * 2 + 1) * 64 + lane;
  const int kr0 = ch0 >> 3, kc0s = ((ch0 & 7) ^ (kr0 & 7)) * 8;
  const int kr1 = ch1 >> 3, kc1s = ((ch1 & 7) ^ (kr1 & 7)) * 8;
  const int kcol = ((lane >> 5) & 1) * 32 + ((lane >> 2) & 3) * 8 +
                   ((lane >> 4) & 1) * 4 + (lane & 3);

#define STAGE_K(buf, kv0)                                                          \
  {                                                                                \
    gload_lds16(qkv + (tokbase + (kv0) + kr0) * RS + 1536 + h * 64 + kc0s,         \
                (char*)Kl + (buf) * 8192 + (wave * 2) * 1024);                     \
    gload_lds16(qkv + (tokbase + (kv0) + kr1) * RS + 1536 + h * 64 + kc1s,         \
                (char*)Kl + (buf) * 8192 + (wave * 2 + 1) * 1024);                 \
  }
#define LOAD_V(kv0)                                                                \
  {                                                                                \
    const unsigned short* vrow = qkv + (tokbase + (kv0) + lane) * RS + 3072 + h * 64; \
    vr[0] = *(const bf16x8*)(vrow + (wave * 2) * 8);                               \
    vr[1] = *(const bf16x8*)(vrow + (wave * 2 + 1) * 8);                           \
  }
#define WRITE_V(buf)                                                               \
  {                                                                                \
    _Pragma("unroll") for (int s = 0; s < 2; ++s) {                                \
      int d0 = (wave * 2 + s) * 8;                                                 \
      _Pragma("unroll") for (int e = 0; e < 8; ++e)                                \
          VT[(buf) * 4608 + (d0 + e) * 72 + kcol] = (unsigned short)vr[s][e];      \
    }                                                                              \
  }

  STAGE_K(0, 0);
  LOAD_V(0);
  asm volatile("s_waitcnt vmcnt(0)" ::: "memory");
  WRITE_V(0);
  __syncthreads();

  int cur = 0;
  for (int t = 0; t < 32; ++t) {
    const int kv0 = t * 64;
    if (t < 31) {
      STAGE_K(cur ^ 1, kv0 + 64);
      LOAD_V(kv0 + 64);
    }

    f32x4 st[4][2];
    const unsigned short* Kb = Kl + cur * 4096;
    __builtin_amdgcn_s_setprio(1);
#pragma unroll
    for (int m = 0; m < 4; ++m) {
      int row = m * 16 + r15;
      int r7 = row & 7;
      bf16x8 ka0 = *(const bf16x8*)&Kb[row * 64 + ((g ^ r7) * 8)];
      bf16x8 ka1 = *(const bf16x8*)&Kb[row * 64 + (((4 + g) ^ r7) * 8)];
#pragma unroll
      for (int qh = 0; qh < 2; ++qh) {
        f32x4 z = {0.f, 0.f, 0.f, 0.f};
        st[m][qh] = mfma16(ka0, qb[qh][0], z);
        st[m][qh] = mfma16(ka1, qb[qh][1], st[m][qh]);
      }
    }
    __builtin_amdgcn_s_setprio(0);

    float pm[2];
#pragma unroll
    for (int qh = 0; qh < 2; ++qh) {
      float t0 = max3f(st[0][qh][0], st[0][qh][1], st[0][qh][2]);
      float t1 = max3f(st[0][qh][3], st[1][qh][0], st[1][qh][1]);
      float t2 = max3f(st[1][qh][2], st[1][qh][3], st[2][qh][0]);
      float t3 = max3f(st[2][qh][1], st[2][qh][2], st[2][qh][3]);
      float t4 = max3f(st[3][qh][0], st[3][qh][1], st[3][qh][2]);
      float p = fmaxf(max3f(t0, t1, t2), max3f(t3, t4, st[3][qh][3]));
      p = fmaxf(p, __shfl_xor(p, 16, 64));
      pm[qh] = fmaxf(p, __shfl_xor(p, 32, 64));
    }

    if (!__all(pm[0] - m_run[0] <= 8.0f && pm[1] - m_run[1] <= 8.0f)) {
#pragma unroll
      for (int qh = 0; qh < 2; ++qh) {
        float mnew = fmaxf(m_run[qh], pm[qh]);
        float fac = fexp2(m_run[qh] - mnew);
        l_run[qh] *= fac;
        float f_i[4];
#pragma unroll
        for (int i = 0; i < 4; ++i)
          f_i[i] = __shfl(fac, (lane & 48) | ((((lane >> 4) & 3) << 2) + i), 64);
#pragma unroll
        for (int dt = 0; dt < 4; ++dt)
#pragma unroll
          for (int i = 0; i < 4; ++i) o[qh][dt][i] *= f_i[i];
        m_run[qh] = mnew;
      }
    }

    unsigned pku[2][4][2];
    float psum[2] = {0.f, 0.f};
#pragma unroll
    for (int m = 0; m < 4; ++m)
#pragma unroll
      for (int qh = 0; qh < 2; ++qh) {
        float p0 = fexp2(st[m][qh][0] - m_run[qh]);
        float p1 = fexp2(st[m][qh][1] - m_run[qh]);
        float p2 = fexp2(st[m][qh][2] - m_run[qh]);
        float p3 = fexp2(st[m][qh][3] - m_run[qh]);
        psum[qh] += (p0 + p1) + (p2 + p3);
        pku[qh][m][0] = cvtpk(p0, p1);
        pku[qh][m][1] = cvtpk(p2, p3);
      }
#pragma unroll
    for (int qh = 0; qh < 2; ++qh) {
      psum[qh] += __shfl_xor(psum[qh], 16, 64);
      psum[qh] += __shfl_xor(psum[qh], 32, 64);
      l_run[qh] += psum[qh];
    }

    const unsigned short* Vb = VT + cur * 4608;
    __builtin_amdgcn_s_setprio(1);
#pragma unroll
    for (int kap = 0; kap < 2; ++kap) {
      union { bf16x8 v; unsigned u[4]; } pa0, pa1;
      pa0.u[0] = pku[0][2 * kap][0];     pa0.u[1] = pku[0][2 * kap][1];
      pa0.u[2] = pku[0][2 * kap + 1][0]; pa0.u[3] = pku[0][2 * kap + 1][1];
      pa1.u[0] = pku[1][2 * kap][0];     pa1.u[1] = pku[1][2 * kap][1];
      pa1.u[2] = pku[1][2 * kap + 1][0]; pa1.u[3] = pku[1][2 * kap + 1][1];
#pragma unroll
      for (int dt = 0; dt < 4; ++dt) {
        bf16x8 vb = *(const bf16x8*)&Vb[(dt * 16 + r15) * 72 + kap * 32 + g * 8];
        o[0][dt] = mfma16(pa0.v, vb, o[0][dt]);
        o[1][dt] = mfma16(pa1.v, vb, o[1][dt]);
      }
    }
    __builtin_amdgcn_s_setprio(0);

    if (t < 31) {
      asm volatile("s_waitcnt vmcnt(0)" ::: "memory");
      WRITE_V(cur ^ 1);
    }
    __syncthreads();
    cur ^= 1;
  }

#pragma unroll
  for (int qh = 0; qh < 2; ++qh) {
    float rl = 1.0f / l_run[qh];
    float r_i[4];
#pragma unroll
    for (int i = 0; i < 4; ++i)
      r_i[i] = __shfl(rl, (lane & 48) | ((((lane >> 4) & 3) << 2) + i), 64);
#pragma unroll
    for (int dt = 0; dt < 4; ++dt)
#pragma unroll
      for (int i = 0; i < 4; ++i) {
        int q = q0 + qh * 16 + ((lane >> 4) << 2) + i;
        int col = h * 64 + dt * 16 + r15;
        attno[(tokbase + q) * 1536 + col] = f2b(o[qh][dt][i] * r_i[i]);
      }
  }
}

extern "C" void kernel_launch(void* const* d_in, const int* in_sizes, int n_in,
                              void* d_out, int out_size, void* d_ws, size_t ws_size,
                              hipStream_t stream) {
  const float* hs = (const float*)d_in[0];
  const float* Wq = (const float*)d_in[1];
  const float* Wk = (const float*)d_in[2];
  const float* Wv = (const float*)d_in[3];
  const float* Wo = (const float*)d_in[4];
  const float* bo = (const float*)d_in[5];
  const float* Mm = (const float*)d_in[6];
  const float* Wr = (const float*)d_in[7];
  const float* Fk = (const float*)d_in[8];
  const float* Fv = (const float*)d_in[9];
  float* out = (float*)d_out;

  unsigned short* hsb   = (unsigned short*)d_ws;
  unsigned short* wqkvt = hsb + (size_t)4096 * 1536;
  unsigned short* qkv   = wqkvt + (size_t)4608 * 1536;
  unsigned short* attno = hsb;
  unsigned short* wot   = wqkvt;

  // strip split-K scratch: 128 slots x 65536 f32 = 33.55 MB after the bf16 buffers
  const size_t base_bytes = ((size_t)4096 * 1536 + (size_t)4608 * 1536 +
                             (size_t)4096 * 4608) * 2;  // 64.49 MB
  float* scratch = (float*)((char*)d_ws + base_bytes);
  const bool split = ws_size >= base_bytes + (size_t)128 * 65536 * 4;

  hipFuncSetAttribute((const void*)k_gemm8,
                      hipFuncAttributeMaxDynamicSharedMemorySize, 131072);

  k_cvt<<<6144, 256, 0, stream>>>(hs, hsb, 1572864);
  k_transpose3<<<1728, 256, 0, stream>>>(Wq, Wk, Wv, wqkvt);

  if (split) {
    k_gemm8<<<384, 512, 131072, stream>>>(hsb, wqkvt, qkv, scratch, 1536, 16, 256);
    k_fixup<<<2048, 256, 0, stream>>>(scratch, qkv);
  } else {
    k_gemm8<<<288, 512, 131072, stream>>>(hsb, wqkvt, qkv, (float*)nullptr, 1536, 18, 288);
  }
  k_transpose<<<576, 256, 0, stream>>>(Wo, wot);  // after gemm8: wot aliases wqkvt
  k_inject<<<4096, 256, 0, stream>>>(Mm, Wr, Fk, Fv, qkv);
  k_attn<<<768, 256, 0, stream>>>(qkv, attno);    // attno aliases hsb
  k_gemm<0><<<32 * 12, 256, 0, stream>>>(attno, wot, (void*)out, bo, 4096, 1536, 1536, 12);
}

// Round 16
// 219.846 us; speedup vs baseline: 1.2670x; 1.0155x over previous
//
#include <hip/hip_runtime.h>
#include <hip/hip_bf16.h>

typedef __attribute__((ext_vector_type(4))) float f32x4;
typedef __attribute__((ext_vector_type(8))) short bf16x8;

#define LOG2E 1.4426950408889634f

__device__ __forceinline__ unsigned short f2b(float f) {
  union { float f; unsigned u; } v; v.f = f;
  unsigned r = v.u + 0x7fffu + ((v.u >> 16) & 1u);
  return (unsigned short)(r >> 16);
}
__device__ __forceinline__ float b2f(unsigned short s) {
  union { unsigned u; float f; } v; v.u = ((unsigned)s) << 16;
  return v.f;
}
__device__ __forceinline__ unsigned cvtpk(float lo, float hi) {
  unsigned r;
  asm("v_cvt_pk_bf16_f32 %0, %1, %2" : "=v"(r) : "v"(lo), "v"(hi));
  return r;
}
__device__ __forceinline__ float fexp2(float x) {
  float r;
  asm("v_exp_f32 %0, %1" : "=v"(r) : "v"(x));
  return r;
}
__device__ __forceinline__ float max3f(float a, float b, float c) {
  return fmaxf(fmaxf(a, b), c);  // clang fuses to v_max3_f32
}
__device__ __forceinline__ void gload_lds16(const void* g, void* l) {
  __builtin_amdgcn_global_load_lds(
      (const __attribute__((address_space(1))) unsigned*)g,
      (__attribute__((address_space(3))) unsigned*)l, 16, 0, 0);
}
__device__ __forceinline__ f32x4 mfma16(bf16x8 a, bf16x8 b, f32x4 c) {
  return __builtin_amdgcn_mfma_f32_16x16x32_bf16(a, b, c, 0, 0, 0);
}

// ---------------- fp32 -> bf16 convert ----------------
__global__ __launch_bounds__(256) void k_cvt(const float* __restrict__ src,
                                             unsigned short* __restrict__ dst, int n4) {
  int i = blockIdx.x * 256 + threadIdx.x;
  if (i >= n4) return;
  float4 v = ((const float4*)src)[i];
  ushort4 o;
  o.x = f2b(v.x); o.y = f2b(v.y); o.z = f2b(v.z); o.w = f2b(v.w);
  ((ushort4*)dst)[i] = o;
}

// ---------------- 1536x1536 transpose fp32 -> bf16 (x3 batched) ----------------
__global__ __launch_bounds__(256) void k_transpose3(const float* __restrict__ s0,
                                                    const float* __restrict__ s1,
                                                    const float* __restrict__ s2,
                                                    unsigned short* __restrict__ dst) {
  __shared__ float tile[64][65];
  const int which = blockIdx.x / 576;
  const int bid = blockIdx.x % 576;
  const float* src = which == 0 ? s0 : (which == 1 ? s1 : s2);
  unsigned short* d = dst + (size_t)which * 1536 * 1536;
  const int tx = threadIdx.x & 63, ty = threadIdx.x >> 6;
  const int r0 = (bid / 24) * 64, c0 = (bid % 24) * 64;
#pragma unroll
  for (int j = 0; j < 16; ++j)
    tile[ty + j * 4][tx] = src[(size_t)(r0 + ty + j * 4) * 1536 + c0 + tx];
  __syncthreads();
#pragma unroll
  for (int j = 0; j < 16; ++j)
    d[(size_t)(c0 + ty + j * 4) * 1536 + r0 + tx] = f2b(tile[tx][ty + j * 4]);
}

__global__ __launch_bounds__(256) void k_transpose(const float* __restrict__ src,
                                                   unsigned short* __restrict__ dst) {
  __shared__ float tile[64][65];
  const int tx = threadIdx.x & 63, ty = threadIdx.x >> 6;
  const int r0 = (blockIdx.x / 24) * 64, c0 = (blockIdx.x % 24) * 64;
#pragma unroll
  for (int j = 0; j < 16; ++j)
    tile[ty + j * 4][tx] = src[(size_t)(r0 + ty + j * 4) * 1536 + c0 + tx];
  __syncthreads();
#pragma unroll
  for (int j = 0; j < 16; ++j)
    dst[(size_t)(c0 + ty + j * 4) * 1536 + r0 + tx] = f2b(tile[tx][ty + j * 4]);
}

// ---------------- m201-style 8-phase 256x256 bf16 GEMM, BK=64, 128KB dyn LDS ----------
// Split-strip mode (nMain=256): blocks [0,256) = main tiles over N in [0,4096),
// full K, bf16 out. Blocks [256,384) = 32 strip tiles (N in [4096,4608)) x 4
// K-slices (K=384 each, NT=6); f32 partials to scratch slot s=tile*4+slice.
// Fallback (nMain=288): original single-grid behavior, no strip.
__global__ __launch_bounds__(512, 2) void k_gemm8(const unsigned short* __restrict__ A,
                                                  const unsigned short* __restrict__ BT,
                                                  unsigned short* __restrict__ C,
                                                  float* __restrict__ scratch,
                                                  int K, int gridNmain, int nMain) {
  extern __shared__ unsigned short lds[];
  unsigned short* As = lds;           // 4 slots x 8192 elems (16KB)
  unsigned short* Bs = lds + 32768;
  const int tid = threadIdx.x;
  const int lane = tid & 63, wave = tid >> 6;
  const int wm = wave >> 2, wn = wave & 3;
  const int r15 = lane & 15, g = lane >> 4;
  const int sw = r15 & 7;

  int bm, bn, kbeg, NT, slot;
  bool partial;
  if ((int)blockIdx.x < nMain) {
    int bid = blockIdx.x;
    int cpx = nMain >> 3;  // bijective XCD swizzle (nMain % 8 == 0)
    bid = (bid & 7) * cpx + (bid >> 3);
    bm = (bid / gridNmain) * 256;
    bn = (bid % gridNmain) * 256;
    kbeg = 0; NT = K >> 6; partial = false; slot = 0;
  } else {
    int s = blockIdx.x - nMain;       // [0,128)
    int tile = s >> 2, slice = s & 3;
    bm = (tile & 15) * 256;
    bn = 4096 + (tile >> 4) * 256;
    kbeg = slice * 384; NT = 6; partial = true; slot = s;
  }
  const unsigned short* Ab = A + kbeg;
  const unsigned short* BTb = BT + kbeg;

  f32x4 acc[8][4] = {};

  auto STAGE = [&](int tl, int part) {
    const bool isB = part >= 2;
    const int half = part & 1;
    const unsigned short* src = isB ? BTb : Ab;
    const int rb = (isB ? bn : bm) + half * 128;
    char* slotp = (char*)(isB ? Bs : As) + ((tl & 1) * 2 + half) * 16384;
#pragma unroll
    for (int i = 0; i < 2; ++i) {
      int cid = i * 512 + tid;
      int row = cid >> 3;
      int logc = (cid & 7) ^ (row & 7);
      gload_lds16(src + (size_t)(rb + row) * K + tl * 64 + logc * 8,
                  slotp + i * 8192 + wave * 1024);
    }
  };

  STAGE(0, 2); STAGE(0, 3); STAGE(0, 0); STAGE(0, 1);
  STAGE(1, 2); STAGE(1, 3); STAGE(1, 0);
  asm volatile("s_waitcnt vmcnt(6)" ::: "memory");
  __builtin_amdgcn_s_barrier();

  bf16x8 af[4][2], bf[4][2];
  for (int t = 0; t < NT; ++t) {
    const int d = t & 1;
    const unsigned short* Aslot = As + (d * 2 + wm) * 8192;
    const unsigned short* Bslot = Bs + (d * 2 + (wn >> 1)) * 8192;
    const int bro = (wn & 1) * 64;

#pragma unroll
    for (int j = 0; j < 4; ++j) {
      const unsigned short* ar = Aslot + (j * 16 + r15) * 64;
      af[j][0] = *(const bf16x8*)(ar + ((g ^ sw) * 8));
      af[j][1] = *(const bf16x8*)(ar + (((4 + g) ^ sw) * 8));
    }
#pragma unroll
    for (int n = 0; n < 2; ++n) {
      const unsigned short* br = Bslot + (bro + n * 16 + r15) * 64;
      bf[n][0] = *(const bf16x8*)(br + ((g ^ sw) * 8));
      bf[n][1] = *(const bf16x8*)(br + (((4 + g) ^ sw) * 8));
    }
    if (t + 1 < NT) STAGE(t + 1, 1);
    __builtin_amdgcn_s_barrier();
    asm volatile("s_waitcnt lgkmcnt(0)" ::: "memory");
    __builtin_amdgcn_sched_barrier(0);
    __builtin_amdgcn_s_setprio(1);
#pragma unroll
    for (int j = 0; j < 4; ++j)
#pragma unroll
      for (int n = 0; n < 2; ++n) {
        acc[j][n] = mfma16(af[j][0], bf[n][0], acc[j][n]);
        acc[j][n] = mfma16(af[j][1], bf[n][1], acc[j][n]);
      }
    __builtin_amdgcn_s_setprio(0);
    __builtin_amdgcn_s_barrier();

#pragma unroll
    for (int n = 2; n < 4; ++n) {
      const unsigned short* br = Bslot + (bro + n * 16 + r15) * 64;
      bf[n][0] = *(const bf16x8*)(br + ((g ^ sw) * 8));
      bf[n][1] = *(const bf16x8*)(br + (((4 + g) ^ sw) * 8));
    }
    __builtin_amdgcn_s_barrier();
    asm volatile("s_waitcnt lgkmcnt(0)" ::: "memory");
    __builtin_amdgcn_sched_barrier(0);
    __builtin_amdgcn_s_setprio(1);
#pragma unroll
    for (int j = 0; j < 4; ++j)
#pragma unroll
      for (int n = 2; n < 4; ++n) {
        acc[j][n] = mfma16(af[j][0], bf[n][0], acc[j][n]);
        acc[j][n] = mfma16(af[j][1], bf[n][1], acc[j][n]);
      }
    __builtin_amdgcn_s_setprio(0);
    __builtin_amdgcn_s_barrier();

#pragma unroll
    for (int j = 0; j < 4; ++j) {
      const unsigned short* ar = Aslot + (64 + j * 16 + r15) * 64;
      af[j][0] = *(const bf16x8*)(ar + ((g ^ sw) * 8));
      af[j][1] = *(const bf16x8*)(ar + (((4 + g) ^ sw) * 8));
    }
    if (t + 2 < NT) STAGE(t + 2, 2);
    __builtin_amdgcn_s_barrier();
    asm volatile("s_waitcnt lgkmcnt(0)" ::: "memory");
    __builtin_amdgcn_sched_barrier(0);
    __builtin_amdgcn_s_setprio(1);
#pragma unroll
    for (int j = 0; j < 4; ++j)
#pragma unroll
      for (int n = 0; n < 2; ++n) {
        acc[4 + j][n] = mfma16(af[j][0], bf[n][0], acc[4 + j][n]);
        acc[4 + j][n] = mfma16(af[j][1], bf[n][1], acc[4 + j][n]);
      }
    __builtin_amdgcn_s_setprio(0);
    __builtin_amdgcn_s_barrier();

    if (t + 2 < NT) { STAGE(t + 2, 3); STAGE(t + 2, 0); }
    __builtin_amdgcn_s_barrier();
    __builtin_amdgcn_s_setprio(1);
#pragma unroll
    for (int j = 0; j < 4; ++j)
#pragma unroll
      for (int n = 2; n < 4; ++n) {
        acc[4 + j][n] = mfma16(af[j][0], bf[n][0], acc[4 + j][n]);
        acc[4 + j][n] = mfma16(af[j][1], bf[n][1], acc[4 + j][n]);
      }
    __builtin_amdgcn_s_setprio(0);
    if (t < NT - 2)
      asm volatile("s_waitcnt vmcnt(6)" ::: "memory");
    else
      asm volatile("s_waitcnt vmcnt(0)" ::: "memory");
    __builtin_amdgcn_s_barrier();
  }

  // epilogue
  if (!partial) {
#pragma unroll
    for (int m = 0; m < 8; ++m)
#pragma unroll
      for (int n = 0; n < 4; ++n)
#pragma unroll
        for (int i = 0; i < 4; ++i) {
          int row = bm + wm * 128 + m * 16 + g * 4 + i;
          int col = bn + wn * 64 + n * 16 + r15;
          C[(size_t)row * 4608 + col] = f2b(acc[m][n][i]);
        }
  } else {
    float* sp = scratch + (size_t)slot * 65536;
#pragma unroll
    for (int m = 0; m < 8; ++m)
#pragma unroll
      for (int n = 0; n < 4; ++n)
#pragma unroll
        for (int i = 0; i < 4; ++i) {
          int rl = wm * 128 + m * 16 + g * 4 + i;
          int cl = wn * 64 + n * 16 + r15;
          sp[rl * 256 + cl] = acc[m][n][i];
        }
  }
}

// ---------------- strip fixup: sum 4 f32 K-slices -> bf16 into qkv ----------------
__global__ __launch_bounds__(256) void k_fixup(const float* __restrict__ scratch,
                                               unsigned short* __restrict__ qkv) {
  size_t gid = (size_t)blockIdx.x * 256 + threadIdx.x;  // 524288 threads x 4 elems
  int tile = (int)(gid >> 14);
  int elem = (int)(gid & 16383) * 4;
  const float* base = scratch + (size_t)tile * 4 * 65536;
  float4 p0 = *(const float4*)(base + elem);
  float4 p1 = *(const float4*)(base + 65536 + elem);
  float4 p2 = *(const float4*)(base + 131072 + elem);
  float4 p3 = *(const float4*)(base + 196608 + elem);
  ushort4 o;
  o.x = f2b(p0.x + p1.x + p2.x + p3.x);
  o.y = f2b(p0.y + p1.y + p2.y + p3.y);
  o.z = f2b(p0.z + p1.z + p2.z + p3.z);
  o.w = f2b(p0.w + p1.w + p2.w + p3.w);
  int r = elem >> 8, c = elem & 255;
  int row = (tile & 15) * 256 + r;
  int col = 4096 + (tile >> 4) * 256 + c;
  *(ushort4*)&qkv[(size_t)row * 4608 + col] = o;
}

// ---------------- bf16 GEMM (m97 pattern) for the output projection ----------------
template <int OUTBF16>
__global__ __launch_bounds__(256) void k_gemm(const unsigned short* __restrict__ A,
                                              const unsigned short* __restrict__ BT,
                                              void* __restrict__ C,
                                              const float* __restrict__ bias,
                                              int M, int N, int K, int gridN) {
  __shared__ unsigned short As[128 * 32];
  __shared__ unsigned short Bs[128 * 32];
  const int tid = threadIdx.x;
  const int lane = tid & 63, wave = tid >> 6;
  int bidx = blockIdx.x;
  {  // bijective XCD swizzle (grid % 8 == 0)
    int cpx = gridDim.x >> 3;
    bidx = (bidx & 7) * cpx + (bidx >> 3);
  }
  const int bm = (bidx / gridN) * 128;
  const int bn = (bidx % gridN) * 128;
  const int wr = (wave >> 1) * 64, wc = (wave & 1) * 64;
  const int r15 = lane & 15, g = lane >> 4;
  const int row0 = tid >> 2, c0 = tid & 3;

  f32x4 acc[4][4] = {};

  for (int k0 = 0; k0 < K; k0 += 32) {
    __syncthreads();
    gload_lds16(A + (size_t)(bm + row0) * K + k0 + c0 * 8, (char*)As + wave * 1024);
    gload_lds16(A + (size_t)(bm + row0 + 64) * K + k0 + c0 * 8,
                (char*)As + 4096 + wave * 1024);
    gload_lds16(BT + (size_t)(bn + row0) * K + k0 + c0 * 8, (char*)Bs + wave * 1024);
    gload_lds16(BT + (size_t)(bn + row0 + 64) * K + k0 + c0 * 8,
                (char*)Bs + 4096 + wave * 1024);
    __syncthreads();
    bf16x8 af[4], bfr[4];
#pragma unroll
    for (int m = 0; m < 4; ++m) {
      af[m] = *(const bf16x8*)&As[(wr + m * 16 + r15) * 32 + g * 8];
      bfr[m] = *(const bf16x8*)&Bs[(wc + m * 16 + r15) * 32 + g * 8];
    }
#pragma unroll
    for (int m = 0; m < 4; ++m)
#pragma unroll
      for (int n = 0; n < 4; ++n)
        acc[m][n] = mfma16(af[m], bfr[n], acc[m][n]);
  }

#pragma unroll
  for (int m = 0; m < 4; ++m)
#pragma unroll
    for (int n = 0; n < 4; ++n)
#pragma unroll
      for (int i = 0; i < 4; ++i) {
        int row = bm + wr + m * 16 + g * 4 + i;
        int col = bn + wc + n * 16 + r15;
        float v = acc[m][n][i];
        if (OUTBF16)
          ((unsigned short*)C)[(size_t)row * N + col] = f2b(v);
        else
          ((float*)C)[(size_t)row * N + col] = v + bias[col];
      }
}

// ---------------- K/V low-rank injection (RMW on bf16 K,V) ----------------
__global__ __launch_bounds__(256) void k_inject(const float* __restrict__ Mm,
                                                const float* __restrict__ Wr,
                                                const float* __restrict__ Fk,
                                                const float* __restrict__ Fv,
                                                unsigned short* __restrict__ qkv) {
  __shared__ float Ml[256];
  __shared__ float gl[4];
  const int bid = blockIdx.x;  // 4096 = B(2)*H(8)*T(4)*NB(64)
  const int nb = bid & 63, t = (bid >> 6) & 3, h = (bid >> 8) & 7, b = bid >> 11;
  const int tid = threadIdx.x;
  const int nl = tid >> 6, d = tid & 63;
  Ml[tid] = Mm[(size_t)(((b * 4 + t) * 256 + nb * 4) * 64) + tid];
  if (tid < 4) gl[tid] = Wr[(b * 4 + t) * 256 + nb * 4 + tid];
  __syncthreads();
  float ak = 0.f, av = 0.f;
#pragma unroll 8
  for (int f = 0; f < 64; ++f) {
    float mv = Ml[nl * 64 + f];
    ak += mv * Fk[(h * 64 + f) * 64 + d];
    av += mv * Fv[(h * 64 + f) * 64 + d];
  }
  float gate = gl[nl];
  ak *= gate; av *= gate;
  const int n = nb * 4 + nl;
  const size_t s0 = (size_t)(b * 2048 + t * 256 + n);
#pragma unroll
  for (int r = 0; r < 2; ++r) {
    size_t row = s0 + (size_t)r * 1024;
    size_t ik = row * 4608 + 1536 + h * 64 + d;
    qkv[ik] = f2b(b2f(qkv[ik]) + ak);
    size_t iv = row * 4608 + 3072 + h * 64 + d;
    qkv[iv] = f2b(b2f(qkv[iv]) + av);
  }
}

// ---------------- flash attention, swapped QK^T, P-in-register ----------------
// Round-15 base (87.2->84.1us) + ISOLATED l-via-MFMA (stride 72 kept, proven
// bit-exact in round 14): denominator accumulated by ones-fragment MFMA on the
// 25%-busy matrix pipe; deletes 24 VALU adds + 4 shfl/iter + epilogue shuffles.
__global__ __launch_bounds__(256, 3) void k_attn(const unsigned short* __restrict__ qkv,
                                                 unsigned short* __restrict__ attno) {
  __shared__ unsigned short Kl[2 * 64 * 64];   // 16 KB
  __shared__ unsigned short VT[2 * 64 * 72];   // 18 KB
  const int tid = threadIdx.x;
  const int lane = tid & 63, wave = tid >> 6;
  const int bid = blockIdx.x;  // 768 = B*24*16
  const int qt = bid & 15;
  const int h = (bid >> 4) % 24;
  const int b = (bid >> 4) / 24;
  const int r15 = lane & 15, g = lane >> 4;
  const int q0 = qt * 128 + wave * 32;
  const size_t RS = 4608;
  const size_t tokbase = (size_t)(b * 2048);

  bf16x8 qb[2][2];
  {
    const float qs = 0.125f * LOG2E;
#pragma unroll
    for (int qh = 0; qh < 2; ++qh) {
      const unsigned short* qrow = qkv + (tokbase + q0 + qh * 16 + r15) * RS + h * 64;
#pragma unroll
      for (int kk = 0; kk < 2; ++kk) {
        bf16x8 v = *(const bf16x8*)(qrow + kk * 32 + g * 8);
#pragma unroll
        for (int e = 0; e < 8; ++e)
          v[e] = (short)f2b(b2f((unsigned short)v[e]) * qs);
        qb[qh][kk] = v;
      }
    }
  }
  bf16x8 ones;
#pragma unroll
  for (int e = 0; e < 8; ++e) ones[e] = (short)0x3F80;  // bf16 1.0

  f32x4 o[2][4] = {};
  f32x4 l_acc[2] = {};
  float m_run[2] = {-1e30f, -1e30f};
  bf16x8 vr[2];

  const int ch0 = wave * 2 * 64 + lane, ch1 = (wave * 2 + 1) * 64 + lane;
  const int kr0 = ch0 >> 3, kc0s = ((ch0 & 7) ^ (kr0 & 7)) * 8;
  const int kr1 = ch1 >> 3, kc1s = ((ch1 & 7) ^ (kr1 & 7)) * 8;
  const int kcol = ((lane >> 5) & 1) * 32 + ((lane >> 2) & 3) * 8 +
                   ((lane >> 4) & 1) * 4 + (lane & 3);

#define STAGE_K(buf, kv0)                                                          \
  {                                                                                \
    gload_lds16(qkv + (tokbase + (kv0) + kr0) * RS + 1536 + h * 64 + kc0s,         \
                (char*)Kl + (buf) * 8192 + (wave * 2) * 1024);                     \
    gload_lds16(qkv + (tokbase + (kv0) + kr1) * RS + 1536 + h * 64 + kc1s,         \
                (char*)Kl + (buf) * 8192 + (wave * 2 + 1) * 1024);                 \
  }
#define LOAD_V(kv0)                                                                \
  {                                                                                \
    const unsigned short* vrow = qkv + (tokbase + (kv0) + lane) * RS + 3072 + h * 64; \
    vr[0] = *(const bf16x8*)(vrow + (wave * 2) * 8);                               \
    vr[1] = *(const bf16x8*)(vrow + (wave * 2 + 1) * 8);                           \
  }
#define WRITE_V(buf)                                                               \
  {                                                                                \
    _Pragma("unroll") for (int s = 0; s < 2; ++s) {                                \
      int d0 = (wave * 2 + s) * 8;                                                 \
      _Pragma("unroll") for (int e = 0; e < 8; ++e)                                \
          VT[(buf) * 4608 + (d0 + e) * 72 + kcol] = (unsigned short)vr[s][e];      \
    }                                                                              \
  }

  STAGE_K(0, 0);
  LOAD_V(0);
  asm volatile("s_waitcnt vmcnt(0)" ::: "memory");
  WRITE_V(0);
  __syncthreads();

  int cur = 0;
  for (int t = 0; t < 32; ++t) {
    const int kv0 = t * 64;
    if (t < 31) {
      STAGE_K(cur ^ 1, kv0 + 64);
      LOAD_V(kv0 + 64);
    }

    f32x4 st[4][2];
    const unsigned short* Kb = Kl + cur * 4096;
    __builtin_amdgcn_s_setprio(1);
#pragma unroll
    for (int m = 0; m < 4; ++m) {
      int row = m * 16 + r15;
      int r7 = row & 7;
      bf16x8 ka0 = *(const bf16x8*)&Kb[row * 64 + ((g ^ r7) * 8)];
      bf16x8 ka1 = *(const bf16x8*)&Kb[row * 64 + (((4 + g) ^ r7) * 8)];
#pragma unroll
      for (int qh = 0; qh < 2; ++qh) {
        f32x4 z = {0.f, 0.f, 0.f, 0.f};
        st[m][qh] = mfma16(ka0, qb[qh][0], z);
        st[m][qh] = mfma16(ka1, qb[qh][1], st[m][qh]);
      }
    }
    __builtin_amdgcn_s_setprio(0);

    float pm[2];
#pragma unroll
    for (int qh = 0; qh < 2; ++qh) {
      float t0 = max3f(st[0][qh][0], st[0][qh][1], st[0][qh][2]);
      float t1 = max3f(st[0][qh][3], st[1][qh][0], st[1][qh][1]);
      float t2 = max3f(st[1][qh][2], st[1][qh][3], st[2][qh][0]);
      float t3 = max3f(st[2][qh][1], st[2][qh][2], st[2][qh][3]);
      float t4 = max3f(st[3][qh][0], st[3][qh][1], st[3][qh][2]);
      float p = fmaxf(max3f(t0, t1, t2), max3f(t3, t4, st[3][qh][3]));
      p = fmaxf(p, __shfl_xor(p, 16, 64));
      pm[qh] = fmaxf(p, __shfl_xor(p, 32, 64));
    }

    if (!__all(pm[0] - m_run[0] <= 8.0f && pm[1] - m_run[1] <= 8.0f)) {
#pragma unroll
      for (int qh = 0; qh < 2; ++qh) {
        float mnew = fmaxf(m_run[qh], pm[qh]);
        float fac = fexp2(m_run[qh] - mnew);
        float f_i[4];
#pragma unroll
        for (int i = 0; i < 4; ++i)
          f_i[i] = __shfl(fac, (lane & 48) | ((((lane >> 4) & 3) << 2) + i), 64);
#pragma unroll
        for (int dt = 0; dt < 4; ++dt)
#pragma unroll
          for (int i = 0; i < 4; ++i) o[qh][dt][i] *= f_i[i];
#pragma unroll
        for (int i = 0; i < 4; ++i) l_acc[qh][i] *= f_i[i];
        m_run[qh] = mnew;
      }
    }

    // P = 2^(st - m); pack to bf16 pairs, kept in registers
    unsigned pku[2][4][2];
#pragma unroll
    for (int m = 0; m < 4; ++m)
#pragma unroll
      for (int qh = 0; qh < 2; ++qh) {
        float p0 = fexp2(st[m][qh][0] - m_run[qh]);
        float p1 = fexp2(st[m][qh][1] - m_run[qh]);
        float p2 = fexp2(st[m][qh][2] - m_run[qh]);
        float p3 = fexp2(st[m][qh][3] - m_run[qh]);
        pku[qh][m][0] = cvtpk(p0, p1);
        pku[qh][m][1] = cvtpk(p2, p3);
      }

    // PV with permuted kv; l accumulated via MFMA with all-ones B fragment
    const unsigned short* Vb = VT + cur * 4608;
    __builtin_amdgcn_s_setprio(1);
#pragma unroll
    for (int kap = 0; kap < 2; ++kap) {
      union { bf16x8 v; unsigned u[4]; } pa0, pa1;
      pa0.u[0] = pku[0][2 * kap][0];     pa0.u[1] = pku[0][2 * kap][1];
      pa0.u[2] = pku[0][2 * kap + 1][0]; pa0.u[3] = pku[0][2 * kap + 1][1];
      pa1.u[0] = pku[1][2 * kap][0];     pa1.u[1] = pku[1][2 * kap][1];
      pa1.u[2] = pku[1][2 * kap + 1][0]; pa1.u[3] = pku[1][2 * kap + 1][1];
#pragma unroll
      for (int dt = 0; dt < 4; ++dt) {
        bf16x8 vb = *(const bf16x8*)&Vb[(dt * 16 + r15) * 72 + kap * 32 + g * 8];
        o[0][dt] = mfma16(pa0.v, vb, o[0][dt]);
        o[1][dt] = mfma16(pa1.v, vb, o[1][dt]);
      }
      l_acc[0] = mfma16(pa0.v, ones, l_acc[0]);
      l_acc[1] = mfma16(pa1.v, ones, l_acc[1]);
    }
    __builtin_amdgcn_s_setprio(0);

    if (t < 31) {
      asm volatile("s_waitcnt vmcnt(0)" ::: "memory");
      WRITE_V(cur ^ 1);
    }
    __syncthreads();
    cur ^= 1;
  }

  // epilogue: l_acc[qh][i] is l for this lane's own q-row (q = 4g+i) - no shuffle
#pragma unroll
  for (int qh = 0; qh < 2; ++qh) {
    float r_i[4];
#pragma unroll
    for (int i = 0; i < 4; ++i) r_i[i] = 1.0f / l_acc[qh][i];
#pragma unroll
    for (int dt = 0; dt < 4; ++dt)
#pragma unroll
      for (int i = 0; i < 4; ++i) {
        int q = q0 + qh * 16 + ((lane >> 4) << 2) + i;
        int col = h * 64 + dt * 16 + r15;
        attno[(tokbase + q) * 1536 + col] = f2b(o[qh][dt][i] * r_i[i]);
      }
  }
}

extern "C" void kernel_launch(void* const* d_in, const int* in_sizes, int n_in,
                              void* d_out, int out_size, void* d_ws, size_t ws_size,
                              hipStream_t stream) {
  const float* hs = (const float*)d_in[0];
  const float* Wq = (const float*)d_in[1];
  const float* Wk = (const float*)d_in[2];
  const float* Wv = (const float*)d_in[3];
  const float* Wo = (const float*)d_in[4];
  const float* bo = (const float*)d_in[5];
  const float* Mm = (const float*)d_in[6];
  const float* Wr = (const float*)d_in[7];
  const float* Fk = (const float*)d_in[8];
  const float* Fv = (const float*)d_in[9];
  float* out = (float*)d_out;

  unsigned short* hsb   = (unsigned short*)d_ws;
  unsigned short* wqkvt = hsb + (size_t)4096 * 1536;
  unsigned short* qkv   = wqkvt + (size_t)4608 * 1536;
  unsigned short* attno = hsb;
  unsigned short* wot   = wqkvt;

  // strip split-K scratch: 128 slots x 65536 f32 = 33.55 MB after the bf16 buffers
  const size_t base_bytes = ((size_t)4096 * 1536 + (size_t)4608 * 1536 +
                             (size_t)4096 * 4608) * 2;  // 64.49 MB
  float* scratch = (float*)((char*)d_ws + base_bytes);
  const bool split = ws_size >= base_bytes + (size_t)128 * 65536 * 4;

  hipFuncSetAttribute((const void*)k_gemm8,
                      hipFuncAttributeMaxDynamicSharedMemorySize, 131072);

  k_cvt<<<6144, 256, 0, stream>>>(hs, hsb, 1572864);
  k_transpose3<<<1728, 256, 0, stream>>>(Wq, Wk, Wv, wqkvt);

  if (split) {
    k_gemm8<<<384, 512, 131072, stream>>>(hsb, wqkvt, qkv, scratch, 1536, 16, 256);
    k_fixup<<<2048, 256, 0, stream>>>(scratch, qkv);
  } else {
    k_gemm8<<<288, 512, 131072, stream>>>(hsb, wqkvt, qkv, (float*)nullptr, 1536, 18, 288);
  }
  k_transpose<<<576, 256, 0, stream>>>(Wo, wot);  // after gemm8: wot aliases wqkvt
  k_inject<<<4096, 256, 0, stream>>>(Mm, Wr, Fk, Fv, qkv);
  k_attn<<<768, 256, 0, stream>>>(qkv, attno);    // attno aliases hsb
  k_gemm<0><<<32 * 12, 256, 0, stream>>>(attno, wot, (void*)out, bo, 4096, 1536, 1536, 12);
}

// Round 17
// 214.443 us; speedup vs baseline: 1.2990x; 1.0252x over previous
//
#include <hip/hip_runtime.h>
#include <hip/hip_bf16.h>

typedef __attribute__((ext_vector_type(4))) float f32x4;
typedef __attribute__((ext_vector_type(8))) short bf16x8;

#define LOG2E 1.4426950408889634f

__device__ __forceinline__ unsigned short f2b(float f) {
  union { float f; unsigned u; } v; v.f = f;
  unsigned r = v.u + 0x7fffu + ((v.u >> 16) & 1u);
  return (unsigned short)(r >> 16);
}
__device__ __forceinline__ float b2f(unsigned short s) {
  union { unsigned u; float f; } v; v.u = ((unsigned)s) << 16;
  return v.f;
}
__device__ __forceinline__ unsigned cvtpk(float lo, float hi) {
  unsigned r;
  asm("v_cvt_pk_bf16_f32 %0, %1, %2" : "=v"(r) : "v"(lo), "v"(hi));
  return r;
}
__device__ __forceinline__ float fexp2(float x) {
  float r;
  asm("v_exp_f32 %0, %1" : "=v"(r) : "v"(x));
  return r;
}
__device__ __forceinline__ float max3f(float a, float b, float c) {
  return fmaxf(fmaxf(a, b), c);  // clang fuses to v_max3_f32
}
__device__ __forceinline__ void gload_lds16(const void* g, void* l) {
  __builtin_amdgcn_global_load_lds(
      (const __attribute__((address_space(1))) unsigned*)g,
      (__attribute__((address_space(3))) unsigned*)l, 16, 0, 0);
}
__device__ __forceinline__ f32x4 mfma16(bf16x8 a, bf16x8 b, f32x4 c) {
  return __builtin_amdgcn_mfma_f32_16x16x32_bf16(a, b, c, 0, 0, 0);
}

// ---------------- fused pre-work: fp32->bf16 cvt (hs)  ||  3x W transpose ----------------
__global__ __launch_bounds__(256) void k_pre(const float* __restrict__ hs,
                                             const float* __restrict__ Wq,
                                             const float* __restrict__ Wk,
                                             const float* __restrict__ Wv,
                                             unsigned short* __restrict__ hsb,
                                             unsigned short* __restrict__ wqkvt) {
  __shared__ float tile[64][65];
  const int bidx = blockIdx.x;
  if (bidx < 6144) {  // cvt: 6144*256*4 elems = 4096*1536
    int i = bidx * 256 + threadIdx.x;
    float4 v = ((const float4*)hs)[i];
    ushort4 o;
    o.x = f2b(v.x); o.y = f2b(v.y); o.z = f2b(v.z); o.w = f2b(v.w);
    ((ushort4*)hsb)[i] = o;
  } else {            // transpose3
    int bb = bidx - 6144;
    const int which = bb / 576;
    const int bid = bb % 576;
    const float* src = which == 0 ? Wq : (which == 1 ? Wk : Wv);
    unsigned short* d = wqkvt + (size_t)which * 1536 * 1536;
    const int tx = threadIdx.x & 63, ty = threadIdx.x >> 6;
    const int r0 = (bid / 24) * 64, c0 = (bid % 24) * 64;
#pragma unroll
    for (int j = 0; j < 16; ++j)
      tile[ty + j * 4][tx] = src[(size_t)(r0 + ty + j * 4) * 1536 + c0 + tx];
    __syncthreads();
#pragma unroll
    for (int j = 0; j < 16; ++j)
      d[(size_t)(c0 + ty + j * 4) * 1536 + r0 + tx] = f2b(tile[tx][ty + j * 4]);
  }
}

// ---------------- fused post-gemm8: Wo transpose || strip fixup || K/V inject ----------
// All three have disjoint outputs: wot buffer; qkv cols [4096,4608); qkv cols
// [1536,2048) u [3072,3584). No ordering needed among them.
__global__ __launch_bounds__(256) void k_post(const float* __restrict__ Wo,
                                              unsigned short* __restrict__ wot,
                                              const float* __restrict__ scratch,
                                              unsigned short* __restrict__ qkv,
                                              const float* __restrict__ Mm,
                                              const float* __restrict__ Wr,
                                              const float* __restrict__ Fk,
                                              const float* __restrict__ Fv) {
  __shared__ float tile[64][65];
  const int bidx = blockIdx.x;
  const int tid = threadIdx.x;
  if (bidx < 576) {  // Wo transpose
    const int tx = tid & 63, ty = tid >> 6;
    const int r0 = (bidx / 24) * 64, c0 = (bidx % 24) * 64;
#pragma unroll
    for (int j = 0; j < 16; ++j)
      tile[ty + j * 4][tx] = Wo[(size_t)(r0 + ty + j * 4) * 1536 + c0 + tx];
    __syncthreads();
#pragma unroll
    for (int j = 0; j < 16; ++j)
      wot[(size_t)(c0 + ty + j * 4) * 1536 + r0 + tx] = f2b(tile[tx][ty + j * 4]);
  } else if (bidx < 576 + 2048) {  // strip fixup
    size_t gid = (size_t)(bidx - 576) * 256 + tid;
    int tl = (int)(gid >> 14);
    int elem = (int)(gid & 16383) * 4;
    const float* base = scratch + (size_t)tl * 4 * 65536;
    float4 p0 = *(const float4*)(base + elem);
    float4 p1 = *(const float4*)(base + 65536 + elem);
    float4 p2 = *(const float4*)(base + 131072 + elem);
    float4 p3 = *(const float4*)(base + 196608 + elem);
    ushort4 o;
    o.x = f2b(p0.x + p1.x + p2.x + p3.x);
    o.y = f2b(p0.y + p1.y + p2.y + p3.y);
    o.z = f2b(p0.z + p1.z + p2.z + p3.z);
    o.w = f2b(p0.w + p1.w + p2.w + p3.w);
    int r = elem >> 8, c = elem & 255;
    int row = (tl & 15) * 256 + r;
    int col = 4096 + (tl >> 4) * 256 + c;
    *(ushort4*)&qkv[(size_t)row * 4608 + col] = o;
  } else {  // K/V low-rank injection
    float* Ml = (float*)tile;          // 256 floats
    float* gl = ((float*)tile) + 256;  // 4 floats
    const int bid = bidx - (576 + 2048);  // [0,4096)
    const int nb = bid & 63, t = (bid >> 6) & 3, h = (bid >> 8) & 7, b = bid >> 11;
    const int nl = tid >> 6, d = tid & 63;
    Ml[tid] = Mm[(size_t)(((b * 4 + t) * 256 + nb * 4) * 64) + tid];
    if (tid < 4) gl[tid] = Wr[(b * 4 + t) * 256 + nb * 4 + tid];
    __syncthreads();
    float ak = 0.f, av = 0.f;
#pragma unroll 8
    for (int f = 0; f < 64; ++f) {
      float mv = Ml[nl * 64 + f];
      ak += mv * Fk[(h * 64 + f) * 64 + d];
      av += mv * Fv[(h * 64 + f) * 64 + d];
    }
    float gate = gl[nl];
    ak *= gate; av *= gate;
    const int n = nb * 4 + nl;
    const size_t s0 = (size_t)(b * 2048 + t * 256 + n);
#pragma unroll
    for (int r = 0; r < 2; ++r) {
      size_t row = s0 + (size_t)r * 1024;
      size_t ik = row * 4608 + 1536 + h * 64 + d;
      qkv[ik] = f2b(b2f(qkv[ik]) + ak);
      size_t iv = row * 4608 + 3072 + h * 64 + d;
      qkv[iv] = f2b(b2f(qkv[iv]) + av);
    }
  }
}

// ---------------- standalone fallback kernels (no-split path) ----------------
__global__ __launch_bounds__(256) void k_transpose(const float* __restrict__ src,
                                                   unsigned short* __restrict__ dst) {
  __shared__ float tile[64][65];
  const int tx = threadIdx.x & 63, ty = threadIdx.x >> 6;
  const int r0 = (blockIdx.x / 24) * 64, c0 = (blockIdx.x % 24) * 64;
#pragma unroll
  for (int j = 0; j < 16; ++j)
    tile[ty + j * 4][tx] = src[(size_t)(r0 + ty + j * 4) * 1536 + c0 + tx];
  __syncthreads();
#pragma unroll
  for (int j = 0; j < 16; ++j)
    dst[(size_t)(c0 + ty + j * 4) * 1536 + r0 + tx] = f2b(tile[tx][ty + j * 4]);
}

__global__ __launch_bounds__(256) void k_inject(const float* __restrict__ Mm,
                                                const float* __restrict__ Wr,
                                                const float* __restrict__ Fk,
                                                const float* __restrict__ Fv,
                                                unsigned short* __restrict__ qkv) {
  __shared__ float Ml[256];
  __shared__ float gl[4];
  const int bid = blockIdx.x;
  const int nb = bid & 63, t = (bid >> 6) & 3, h = (bid >> 8) & 7, b = bid >> 11;
  const int tid = threadIdx.x;
  const int nl = tid >> 6, d = tid & 63;
  Ml[tid] = Mm[(size_t)(((b * 4 + t) * 256 + nb * 4) * 64) + tid];
  if (tid < 4) gl[tid] = Wr[(b * 4 + t) * 256 + nb * 4 + tid];
  __syncthreads();
  float ak = 0.f, av = 0.f;
#pragma unroll 8
  for (int f = 0; f < 64; ++f) {
    float mv = Ml[nl * 64 + f];
    ak += mv * Fk[(h * 64 + f) * 64 + d];
    av += mv * Fv[(h * 64 + f) * 64 + d];
  }
  float gate = gl[nl];
  ak *= gate; av *= gate;
  const int n = nb * 4 + nl;
  const size_t s0 = (size_t)(b * 2048 + t * 256 + n);
#pragma unroll
  for (int r = 0; r < 2; ++r) {
    size_t row = s0 + (size_t)r * 1024;
    size_t ik = row * 4608 + 1536 + h * 64 + d;
    qkv[ik] = f2b(b2f(qkv[ik]) + ak);
    size_t iv = row * 4608 + 3072 + h * 64 + d;
    qkv[iv] = f2b(b2f(qkv[iv]) + av);
  }
}

// ---------------- m201-style 8-phase 256x256 bf16 GEMM, BK=64, 128KB dyn LDS ----------
__global__ __launch_bounds__(512, 2) void k_gemm8(const unsigned short* __restrict__ A,
                                                  const unsigned short* __restrict__ BT,
                                                  unsigned short* __restrict__ C,
                                                  float* __restrict__ scratch,
                                                  int K, int gridNmain, int nMain) {
  extern __shared__ unsigned short lds[];
  unsigned short* As = lds;           // 4 slots x 8192 elems (16KB)
  unsigned short* Bs = lds + 32768;
  const int tid = threadIdx.x;
  const int lane = tid & 63, wave = tid >> 6;
  const int wm = wave >> 2, wn = wave & 3;
  const int r15 = lane & 15, g = lane >> 4;
  const int sw = r15 & 7;

  int bm, bn, kbeg, NT, slot;
  bool partial;
  if ((int)blockIdx.x < nMain) {
    int bid = blockIdx.x;
    int cpx = nMain >> 3;  // bijective XCD swizzle (nMain % 8 == 0)
    bid = (bid & 7) * cpx + (bid >> 3);
    bm = (bid / gridNmain) * 256;
    bn = (bid % gridNmain) * 256;
    kbeg = 0; NT = K >> 6; partial = false; slot = 0;
  } else {
    int s = blockIdx.x - nMain;       // [0,128)
    int tile = s >> 2, slice = s & 3;
    bm = (tile & 15) * 256;
    bn = 4096 + (tile >> 4) * 256;
    kbeg = slice * 384; NT = 6; partial = true; slot = s;
  }
  const unsigned short* Ab = A + kbeg;
  const unsigned short* BTb = BT + kbeg;

  f32x4 acc[8][4] = {};

  auto STAGE = [&](int tl, int part) {
    const bool isB = part >= 2;
    const int half = part & 1;
    const unsigned short* src = isB ? BTb : Ab;
    const int rb = (isB ? bn : bm) + half * 128;
    char* slotp = (char*)(isB ? Bs : As) + ((tl & 1) * 2 + half) * 16384;
#pragma unroll
    for (int i = 0; i < 2; ++i) {
      int cid = i * 512 + tid;
      int row = cid >> 3;
      int logc = (cid & 7) ^ (row & 7);
      gload_lds16(src + (size_t)(rb + row) * K + tl * 64 + logc * 8,
                  slotp + i * 8192 + wave * 1024);
    }
  };

  STAGE(0, 2); STAGE(0, 3); STAGE(0, 0); STAGE(0, 1);
  STAGE(1, 2); STAGE(1, 3); STAGE(1, 0);
  asm volatile("s_waitcnt vmcnt(6)" ::: "memory");
  __builtin_amdgcn_s_barrier();

  bf16x8 af[4][2], bf[4][2];
  for (int t = 0; t < NT; ++t) {
    const int d = t & 1;
    const unsigned short* Aslot = As + (d * 2 + wm) * 8192;
    const unsigned short* Bslot = Bs + (d * 2 + (wn >> 1)) * 8192;
    const int bro = (wn & 1) * 64;

#pragma unroll
    for (int j = 0; j < 4; ++j) {
      const unsigned short* ar = Aslot + (j * 16 + r15) * 64;
      af[j][0] = *(const bf16x8*)(ar + ((g ^ sw) * 8));
      af[j][1] = *(const bf16x8*)(ar + (((4 + g) ^ sw) * 8));
    }
#pragma unroll
    for (int n = 0; n < 2; ++n) {
      const unsigned short* br = Bslot + (bro + n * 16 + r15) * 64;
      bf[n][0] = *(const bf16x8*)(br + ((g ^ sw) * 8));
      bf[n][1] = *(const bf16x8*)(br + (((4 + g) ^ sw) * 8));
    }
    if (t + 1 < NT) STAGE(t + 1, 1);
    __builtin_amdgcn_s_barrier();
    asm volatile("s_waitcnt lgkmcnt(0)" ::: "memory");
    __builtin_amdgcn_sched_barrier(0);
    __builtin_amdgcn_s_setprio(1);
#pragma unroll
    for (int j = 0; j < 4; ++j)
#pragma unroll
      for (int n = 0; n < 2; ++n) {
        acc[j][n] = mfma16(af[j][0], bf[n][0], acc[j][n]);
        acc[j][n] = mfma16(af[j][1], bf[n][1], acc[j][n]);
      }
    __builtin_amdgcn_s_setprio(0);
    __builtin_amdgcn_s_barrier();

#pragma unroll
    for (int n = 2; n < 4; ++n) {
      const unsigned short* br = Bslot + (bro + n * 16 + r15) * 64;
      bf[n][0] = *(const bf16x8*)(br + ((g ^ sw) * 8));
      bf[n][1] = *(const bf16x8*)(br + (((4 + g) ^ sw) * 8));
    }
    __builtin_amdgcn_s_barrier();
    asm volatile("s_waitcnt lgkmcnt(0)" ::: "memory");
    __builtin_amdgcn_sched_barrier(0);
    __builtin_amdgcn_s_setprio(1);
#pragma unroll
    for (int j = 0; j < 4; ++j)
#pragma unroll
      for (int n = 2; n < 4; ++n) {
        acc[j][n] = mfma16(af[j][0], bf[n][0], acc[j][n]);
        acc[j][n] = mfma16(af[j][1], bf[n][1], acc[j][n]);
      }
    __builtin_amdgcn_s_setprio(0);
    __builtin_amdgcn_s_barrier();

#pragma unroll
    for (int j = 0; j < 4; ++j) {
      const unsigned short* ar = Aslot + (64 + j * 16 + r15) * 64;
      af[j][0] = *(const bf16x8*)(ar + ((g ^ sw) * 8));
      af[j][1] = *(const bf16x8*)(ar + (((4 + g) ^ sw) * 8));
    }
    if (t + 2 < NT) STAGE(t + 2, 2);
    __builtin_amdgcn_s_barrier();
    asm volatile("s_waitcnt lgkmcnt(0)" ::: "memory");
    __builtin_amdgcn_sched_barrier(0);
    __builtin_amdgcn_s_setprio(1);
#pragma unroll
    for (int j = 0; j < 4; ++j)
#pragma unroll
      for (int n = 0; n < 2; ++n) {
        acc[4 + j][n] = mfma16(af[j][0], bf[n][0], acc[4 + j][n]);
        acc[4 + j][n] = mfma16(af[j][1], bf[n][1], acc[4 + j][n]);
      }
    __builtin_amdgcn_s_setprio(0);
    __builtin_amdgcn_s_barrier();

    if (t + 2 < NT) { STAGE(t + 2, 3); STAGE(t + 2, 0); }
    __builtin_amdgcn_s_barrier();
    __builtin_amdgcn_s_setprio(1);
#pragma unroll
    for (int j = 0; j < 4; ++j)
#pragma unroll
      for (int n = 2; n < 4; ++n) {
        acc[4 + j][n] = mfma16(af[j][0], bf[n][0], acc[4 + j][n]);
        acc[4 + j][n] = mfma16(af[j][1], bf[n][1], acc[4 + j][n]);
      }
    __builtin_amdgcn_s_setprio(0);
    if (t < NT - 2)
      asm volatile("s_waitcnt vmcnt(6)" ::: "memory");
    else
      asm volatile("s_waitcnt vmcnt(0)" ::: "memory");
    __builtin_amdgcn_s_barrier();
  }

  // epilogue
  if (!partial) {
#pragma unroll
    for (int m = 0; m < 8; ++m)
#pragma unroll
      for (int n = 0; n < 4; ++n)
#pragma unroll
        for (int i = 0; i < 4; ++i) {
          int row = bm + wm * 128 + m * 16 + g * 4 + i;
          int col = bn + wn * 64 + n * 16 + r15;
          C[(size_t)row * 4608 + col] = f2b(acc[m][n][i]);
        }
  } else {
    float* sp = scratch + (size_t)slot * 65536;
#pragma unroll
    for (int m = 0; m < 8; ++m)
#pragma unroll
      for (int n = 0; n < 4; ++n)
#pragma unroll
        for (int i = 0; i < 4; ++i) {
          int rl = wm * 128 + m * 16 + g * 4 + i;
          int cl = wn * 64 + n * 16 + r15;
          sp[rl * 256 + cl] = acc[m][n][i];
        }
  }
}

// ---------------- strip fixup (fallback standalone; fused copy in k_post) ----------
__global__ __launch_bounds__(256) void k_fixup(const float* __restrict__ scratch,
                                               unsigned short* __restrict__ qkv) {
  size_t gid = (size_t)blockIdx.x * 256 + threadIdx.x;
  int tile = (int)(gid >> 14);
  int elem = (int)(gid & 16383) * 4;
  const float* base = scratch + (size_t)tile * 4 * 65536;
  float4 p0 = *(const float4*)(base + elem);
  float4 p1 = *(const float4*)(base + 65536 + elem);
  float4 p2 = *(const float4*)(base + 131072 + elem);
  float4 p3 = *(const float4*)(base + 196608 + elem);
  ushort4 o;
  o.x = f2b(p0.x + p1.x + p2.x + p3.x);
  o.y = f2b(p0.y + p1.y + p2.y + p3.y);
  o.z = f2b(p0.z + p1.z + p2.z + p3.z);
  o.w = f2b(p0.w + p1.w + p2.w + p3.w);
  int r = elem >> 8, c = elem & 255;
  int row = (tile & 15) * 256 + r;
  int col = 4096 + (tile >> 4) * 256 + c;
  *(ushort4*)&qkv[(size_t)row * 4608 + col] = o;
}

// ---------------- bf16 GEMM (m97 pattern) for the output projection ----------------
template <int OUTBF16>
__global__ __launch_bounds__(256) void k_gemm(const unsigned short* __restrict__ A,
                                              const unsigned short* __restrict__ BT,
                                              void* __restrict__ C,
                                              const float* __restrict__ bias,
                                              int M, int N, int K, int gridN) {
  __shared__ unsigned short As[128 * 32];
  __shared__ unsigned short Bs[128 * 32];
  const int tid = threadIdx.x;
  const int lane = tid & 63, wave = tid >> 6;
  int bidx = blockIdx.x;
  {  // bijective XCD swizzle (grid % 8 == 0)
    int cpx = gridDim.x >> 3;
    bidx = (bidx & 7) * cpx + (bidx >> 3);
  }
  const int bm = (bidx / gridN) * 128;
  const int bn = (bidx % gridN) * 128;
  const int wr = (wave >> 1) * 64, wc = (wave & 1) * 64;
  const int r15 = lane & 15, g = lane >> 4;
  const int row0 = tid >> 2, c0 = tid & 3;

  f32x4 acc[4][4] = {};

  for (int k0 = 0; k0 < K; k0 += 32) {
    __syncthreads();
    gload_lds16(A + (size_t)(bm + row0) * K + k0 + c0 * 8, (char*)As + wave * 1024);
    gload_lds16(A + (size_t)(bm + row0 + 64) * K + k0 + c0 * 8,
                (char*)As + 4096 + wave * 1024);
    gload_lds16(BT + (size_t)(bn + row0) * K + k0 + c0 * 8, (char*)Bs + wave * 1024);
    gload_lds16(BT + (size_t)(bn + row0 + 64) * K + k0 + c0 * 8,
                (char*)Bs + 4096 + wave * 1024);
    __syncthreads();
    bf16x8 af[4], bfr[4];
#pragma unroll
    for (int m = 0; m < 4; ++m) {
      af[m] = *(const bf16x8*)&As[(wr + m * 16 + r15) * 32 + g * 8];
      bfr[m] = *(const bf16x8*)&Bs[(wc + m * 16 + r15) * 32 + g * 8];
    }
#pragma unroll
    for (int m = 0; m < 4; ++m)
#pragma unroll
      for (int n = 0; n < 4; ++n)
        acc[m][n] = mfma16(af[m], bfr[n], acc[m][n]);
  }

#pragma unroll
  for (int m = 0; m < 4; ++m)
#pragma unroll
    for (int n = 0; n < 4; ++n)
#pragma unroll
      for (int i = 0; i < 4; ++i) {
        int row = bm + wr + m * 16 + g * 4 + i;
        int col = bn + wc + n * 16 + r15;
        float v = acc[m][n][i];
        if (OUTBF16)
          ((unsigned short*)C)[(size_t)row * N + col] = f2b(v);
        else
          ((float*)C)[(size_t)row * N + col] = v + bias[col];
      }
}

// ---------------- flash attention, swapped QK^T, P-in-register ----------------
// Round-16 version (77.9us): max3 tree + l-via-MFMA (ones fragment), stride 72.
__global__ __launch_bounds__(256, 3) void k_attn(const unsigned short* __restrict__ qkv,
                                                 unsigned short* __restrict__ attno) {
  __shared__ unsigned short Kl[2 * 64 * 64];   // 16 KB
  __shared__ unsigned short VT[2 * 64 * 72];   // 18 KB
  const int tid = threadIdx.x;
  const int lane = tid & 63, wave = tid >> 6;
  const int bid = blockIdx.x;  // 768 = B*24*16
  const int qt = bid & 15;
  const int h = (bid >> 4) % 24;
  const int b = (bid >> 4) / 24;
  const int r15 = lane & 15, g = lane >> 4;
  const int q0 = qt * 128 + wave * 32;
  const size_t RS = 4608;
  const size_t tokbase = (size_t)(b * 2048);

  bf16x8 qb[2][2];
  {
    const float qs = 0.125f * LOG2E;
#pragma unroll
    for (int qh = 0; qh < 2; ++qh) {
      const unsigned short* qrow = qkv + (tokbase + q0 + qh * 16 + r15) * RS + h * 64;
#pragma unroll
      for (int kk = 0; kk < 2; ++kk) {
        bf16x8 v = *(const bf16x8*)(qrow + kk * 32 + g * 8);
#pragma unroll
        for (int e = 0; e < 8; ++e)
          v[e] = (short)f2b(b2f((unsigned short)v[e]) * qs);
        qb[qh][kk] = v;
      }
    }
  }
  bf16x8 ones;
#pragma unroll
  for (int e = 0; e < 8; ++e) ones[e] = (short)0x3F80;  // bf16 1.0

  f32x4 o[2][4] = {};
  f32x4 l_acc[2] = {};
  float m_run[2] = {-1e30f, -1e30f};
  bf16x8 vr[2];

  const int ch0 = wave * 2 * 64 + lane, ch1 = (wave * 2 + 1) * 64 + lane;
  const int kr0 = ch0 >> 3, kc0s = ((ch0 & 7) ^ (kr0 & 7)) * 8;
  const int kr1 = ch1 >> 3, kc1s = ((ch1 & 7) ^ (kr1 & 7)) * 8;
  const int kcol = ((lane >> 5) & 1) * 32 + ((lane >> 2) & 3) * 8 +
                   ((lane >> 4) & 1) * 4 + (lane & 3);

#define STAGE_K(buf, kv0)                                                          \
  {                                                                                \
    gload_lds16(qkv + (tokbase + (kv0) + kr0) * RS + 1536 + h * 64 + kc0s,         \
                (char*)Kl + (buf) * 8192 + (wave * 2) * 1024);                     \
    gload_lds16(qkv + (tokbase + (kv0) + kr1) * RS + 1536 + h * 64 + kc1s,         \
                (char*)Kl + (buf) * 8192 + (wave * 2 + 1) * 1024);                 \
  }
#define LOAD_V(kv0)                                                                \
  {                                                                                \
    const unsigned short* vrow = qkv + (tokbase + (kv0) + lane) * RS + 3072 + h * 64; \
    vr[0] = *(const bf16x8*)(vrow + (wave * 2) * 8);                               \
    vr[1] = *(const bf16x8*)(vrow + (wave * 2 + 1) * 8);                           \
  }
#define WRITE_V(buf)                                                               \
  {                                                                                \
    _Pragma("unroll") for (int s = 0; s < 2; ++s) {                                \
      int d0 = (wave * 2 + s) * 8;                                                 \
      _Pragma("unroll") for (int e = 0; e < 8; ++e)                                \
          VT[(buf) * 4608 + (d0 + e) * 72 + kcol] = (unsigned short)vr[s][e];      \
    }                                                                              \
  }

  STAGE_K(0, 0);
  LOAD_V(0);
  asm volatile("s_waitcnt vmcnt(0)" ::: "memory");
  WRITE_V(0);
  __syncthreads();

  int cur = 0;
  for (int t = 0; t < 32; ++t) {
    const int kv0 = t * 64;
    if (t < 31) {
      STAGE_K(cur ^ 1, kv0 + 64);
      LOAD_V(kv0 + 64);
    }

    f32x4 st[4][2];
    const unsigned short* Kb = Kl + cur * 4096;
    __builtin_amdgcn_s_setprio(1);
#pragma unroll
    for (int m = 0; m < 4; ++m) {
      int row = m * 16 + r15;
      int r7 = row & 7;
      bf16x8 ka0 = *(const bf16x8*)&Kb[row * 64 + ((g ^ r7) * 8)];
      bf16x8 ka1 = *(const bf16x8*)&Kb[row * 64 + (((4 + g) ^ r7) * 8)];
#pragma unroll
      for (int qh = 0; qh < 2; ++qh) {
        f32x4 z = {0.f, 0.f, 0.f, 0.f};
        st[m][qh] = mfma16(ka0, qb[qh][0], z);
        st[m][qh] = mfma16(ka1, qb[qh][1], st[m][qh]);
      }
    }
    __builtin_amdgcn_s_setprio(0);

    float pm[2];
#pragma unroll
    for (int qh = 0; qh < 2; ++qh) {
      float t0 = max3f(st[0][qh][0], st[0][qh][1], st[0][qh][2]);
      float t1 = max3f(st[0][qh][3], st[1][qh][0], st[1][qh][1]);
      float t2 = max3f(st[1][qh][2], st[1][qh][3], st[2][qh][0]);
      float t3 = max3f(st[2][qh][1], st[2][qh][2], st[2][qh][3]);
      float t4 = max3f(st[3][qh][0], st[3][qh][1], st[3][qh][2]);
      float p = fmaxf(max3f(t0, t1, t2), max3f(t3, t4, st[3][qh][3]));
      p = fmaxf(p, __shfl_xor(p, 16, 64));
      pm[qh] = fmaxf(p, __shfl_xor(p, 32, 64));
    }

    if (!__all(pm[0] - m_run[0] <= 8.0f && pm[1] - m_run[1] <= 8.0f)) {
#pragma unroll
      for (int qh = 0; qh < 2; ++qh) {
        float mnew = fmaxf(m_run[qh], pm[qh]);
        float fac = fexp2(m_run[qh] - mnew);
        float f_i[4];
#pragma unroll
        for (int i = 0; i < 4; ++i)
          f_i[i] = __shfl(fac, (lane & 48) | ((((lane >> 4) & 3) << 2) + i), 64);
#pragma unroll
        for (int dt = 0; dt < 4; ++dt)
#pragma unroll
          for (int i = 0; i < 4; ++i) o[qh][dt][i] *= f_i[i];
#pragma unroll
        for (int i = 0; i < 4; ++i) l_acc[qh][i] *= f_i[i];
        m_run[qh] = mnew;
      }
    }

    unsigned pku[2][4][2];
#pragma unroll
    for (int m = 0; m < 4; ++m)
#pragma unroll
      for (int qh = 0; qh < 2; ++qh) {
        float p0 = fexp2(st[m][qh][0] - m_run[qh]);
        float p1 = fexp2(st[m][qh][1] - m_run[qh]);
        float p2 = fexp2(st[m][qh][2] - m_run[qh]);
        float p3 = fexp2(st[m][qh][3] - m_run[qh]);
        pku[qh][m][0] = cvtpk(p0, p1);
        pku[qh][m][1] = cvtpk(p2, p3);
      }

    const unsigned short* Vb = VT + cur * 4608;
    __builtin_amdgcn_s_setprio(1);
#pragma unroll
    for (int kap = 0; kap < 2; ++kap) {
      union { bf16x8 v; unsigned u[4]; } pa0, pa1;
      pa0.u[0] = pku[0][2 * kap][0];     pa0.u[1] = pku[0][2 * kap][1];
      pa0.u[2] = pku[0][2 * kap + 1][0]; pa0.u[3] = pku[0][2 * kap + 1][1];
      pa1.u[0] = pku[1][2 * kap][0];     pa1.u[1] = pku[1][2 * kap][1];
      pa1.u[2] = pku[1][2 * kap + 1][0]; pa1.u[3] = pku[1][2 * kap + 1][1];
#pragma unroll
      for (int dt = 0; dt < 4; ++dt) {
        bf16x8 vb = *(const bf16x8*)&Vb[(dt * 16 + r15) * 72 + kap * 32 + g * 8];
        o[0][dt] = mfma16(pa0.v, vb, o[0][dt]);
        o[1][dt] = mfma16(pa1.v, vb, o[1][dt]);
      }
      l_acc[0] = mfma16(pa0.v, ones, l_acc[0]);
      l_acc[1] = mfma16(pa1.v, ones, l_acc[1]);
    }
    __builtin_amdgcn_s_setprio(0);

    if (t < 31) {
      asm volatile("s_waitcnt vmcnt(0)" ::: "memory");
      WRITE_V(cur ^ 1);
    }
    __syncthreads();
    cur ^= 1;
  }

#pragma unroll
  for (int qh = 0; qh < 2; ++qh) {
    float r_i[4];
#pragma unroll
    for (int i = 0; i < 4; ++i) r_i[i] = 1.0f / l_acc[qh][i];
#pragma unroll
    for (int dt = 0; dt < 4; ++dt)
#pragma unroll
      for (int i = 0; i < 4; ++i) {
        int q = q0 + qh * 16 + ((lane >> 4) << 2) + i;
        int col = h * 64 + dt * 16 + r15;
        attno[(tokbase + q) * 1536 + col] = f2b(o[qh][dt][i] * r_i[i]);
      }
  }
}

extern "C" void kernel_launch(void* const* d_in, const int* in_sizes, int n_in,
                              void* d_out, int out_size, void* d_ws, size_t ws_size,
                              hipStream_t stream) {
  const float* hs = (const float*)d_in[0];
  const float* Wq = (const float*)d_in[1];
  const float* Wk = (const float*)d_in[2];
  const float* Wv = (const float*)d_in[3];
  const float* Wo = (const float*)d_in[4];
  const float* bo = (const float*)d_in[5];
  const float* Mm = (const float*)d_in[6];
  const float* Wr = (const float*)d_in[7];
  const float* Fk = (const float*)d_in[8];
  const float* Fv = (const float*)d_in[9];
  float* out = (float*)d_out;

  unsigned short* hsb   = (unsigned short*)d_ws;
  unsigned short* wqkvt = hsb + (size_t)4096 * 1536;
  unsigned short* qkv   = wqkvt + (size_t)4608 * 1536;
  unsigned short* attno = hsb;
  unsigned short* wot   = wqkvt;

  const size_t base_bytes = ((size_t)4096 * 1536 + (size_t)4608 * 1536 +
                             (size_t)4096 * 4608) * 2;  // 64.49 MB
  float* scratch = (float*)((char*)d_ws + base_bytes);
  const bool split = ws_size >= base_bytes + (size_t)128 * 65536 * 4;

  hipFuncSetAttribute((const void*)k_gemm8,
                      hipFuncAttributeMaxDynamicSharedMemorySize, 131072);

  k_pre<<<7872, 256, 0, stream>>>(hs, Wq, Wk, Wv, hsb, wqkvt);

  if (split) {
    k_gemm8<<<384, 512, 131072, stream>>>(hsb, wqkvt, qkv, scratch, 1536, 16, 256);
    // wot aliases wqkvt (dead after gemm8); fixup/inject/Wo-transpose all
    // post-gemm8, mutually independent (disjoint outputs) -> one fused launch
    k_post<<<6720, 256, 0, stream>>>(Wo, wot, scratch, qkv, Mm, Wr, Fk, Fv);
  } else {
    k_gemm8<<<288, 512, 131072, stream>>>(hsb, wqkvt, qkv, (float*)nullptr, 1536, 18, 288);
    k_transpose<<<576, 256, 0, stream>>>(Wo, wot);
    k_inject<<<4096, 256, 0, stream>>>(Mm, Wr, Fk, Fv, qkv);
  }
  k_attn<<<768, 256, 0, stream>>>(qkv, attno);    // attno aliases hsb
  k_gemm<0><<<32 * 12, 256, 0, stream>>>(attno, wot, (void*)out, bo, 4096, 1536, 1536, 12);
}

// Round 18
// 213.482 us; speedup vs baseline: 1.3048x; 1.0045x over previous
//
#include <hip/hip_runtime.h>
#include <hip/hip_bf16.h>

typedef __attribute__((ext_vector_type(4))) float f32x4;
typedef __attribute__((ext_vector_type(8))) short bf16x8;

#define LOG2E 1.4426950408889634f

__device__ __forceinline__ unsigned short f2b(float f) {
  union { float f; unsigned u; } v; v.f = f;
  unsigned r = v.u + 0x7fffu + ((v.u >> 16) & 1u);
  return (unsigned short)(r >> 16);
}
__device__ __forceinline__ float b2f(unsigned short s) {
  union { unsigned u; float f; } v; v.u = ((unsigned)s) << 16;
  return v.f;
}
__device__ __forceinline__ unsigned cvtpk(float lo, float hi) {
  unsigned r;
  asm("v_cvt_pk_bf16_f32 %0, %1, %2" : "=v"(r) : "v"(lo), "v"(hi));
  return r;
}
__device__ __forceinline__ float fexp2(float x) {
  float r;
  asm("v_exp_f32 %0, %1" : "=v"(r) : "v"(x));
  return r;
}
__device__ __forceinline__ float max3f(float a, float b, float c) {
  return fmaxf(fmaxf(a, b), c);  // clang fuses to v_max3_f32
}
__device__ __forceinline__ void gload_lds16(const void* g, void* l) {
  __builtin_amdgcn_global_load_lds(
      (const __attribute__((address_space(1))) unsigned*)g,
      (__attribute__((address_space(3))) unsigned*)l, 16, 0, 0);
}
__device__ __forceinline__ f32x4 mfma16(bf16x8 a, bf16x8 b, f32x4 c) {
  return __builtin_amdgcn_mfma_f32_16x16x32_bf16(a, b, c, 0, 0, 0);
}

// ---------------- fused pre-work: fp32->bf16 cvt (hs)  ||  3x W transpose ----------------
__global__ __launch_bounds__(256) void k_pre(const float* __restrict__ hs,
                                             const float* __restrict__ Wq,
                                             const float* __restrict__ Wk,
                                             const float* __restrict__ Wv,
                                             unsigned short* __restrict__ hsb,
                                             unsigned short* __restrict__ wqkvt) {
  __shared__ float tile[64][65];
  const int bidx = blockIdx.x;
  if (bidx < 6144) {  // cvt: 6144*256*4 elems = 4096*1536
    int i = bidx * 256 + threadIdx.x;
    float4 v = ((const float4*)hs)[i];
    ushort4 o;
    o.x = f2b(v.x); o.y = f2b(v.y); o.z = f2b(v.z); o.w = f2b(v.w);
    ((ushort4*)hsb)[i] = o;
  } else {            // transpose3
    int bb = bidx - 6144;
    const int which = bb / 576;
    const int bid = bb % 576;
    const float* src = which == 0 ? Wq : (which == 1 ? Wk : Wv);
    unsigned short* d = wqkvt + (size_t)which * 1536 * 1536;
    const int tx = threadIdx.x & 63, ty = threadIdx.x >> 6;
    const int r0 = (bid / 24) * 64, c0 = (bid % 24) * 64;
#pragma unroll
    for (int j = 0; j < 16; ++j)
      tile[ty + j * 4][tx] = src[(size_t)(r0 + ty + j * 4) * 1536 + c0 + tx];
    __syncthreads();
#pragma unroll
    for (int j = 0; j < 16; ++j)
      d[(size_t)(c0 + ty + j * 4) * 1536 + r0 + tx] = f2b(tile[tx][ty + j * 4]);
  }
}

// ---------------- fused post-gemm8: Wo transpose || strip fixup || K/V inject ----------
__global__ __launch_bounds__(256) void k_post(const float* __restrict__ Wo,
                                              unsigned short* __restrict__ wot,
                                              const float* __restrict__ scratch,
                                              unsigned short* __restrict__ qkv,
                                              const float* __restrict__ Mm,
                                              const float* __restrict__ Wr,
                                              const float* __restrict__ Fk,
                                              const float* __restrict__ Fv) {
  __shared__ float tile[64][65];
  const int bidx = blockIdx.x;
  const int tid = threadIdx.x;
  if (bidx < 576) {  // Wo transpose
    const int tx = tid & 63, ty = tid >> 6;
    const int r0 = (bidx / 24) * 64, c0 = (bidx % 24) * 64;
#pragma unroll
    for (int j = 0; j < 16; ++j)
      tile[ty + j * 4][tx] = Wo[(size_t)(r0 + ty + j * 4) * 1536 + c0 + tx];
    __syncthreads();
#pragma unroll
    for (int j = 0; j < 16; ++j)
      wot[(size_t)(c0 + ty + j * 4) * 1536 + r0 + tx] = f2b(tile[tx][ty + j * 4]);
  } else if (bidx < 576 + 2048) {  // strip fixup
    size_t gid = (size_t)(bidx - 576) * 256 + tid;
    int tl = (int)(gid >> 14);
    int elem = (int)(gid & 16383) * 4;
    const float* base = scratch + (size_t)tl * 4 * 65536;
    float4 p0 = *(const float4*)(base + elem);
    float4 p1 = *(const float4*)(base + 65536 + elem);
    float4 p2 = *(const float4*)(base + 131072 + elem);
    float4 p3 = *(const float4*)(base + 196608 + elem);
    ushort4 o;
    o.x = f2b(p0.x + p1.x + p2.x + p3.x);
    o.y = f2b(p0.y + p1.y + p2.y + p3.y);
    o.z = f2b(p0.z + p1.z + p2.z + p3.z);
    o.w = f2b(p0.w + p1.w + p2.w + p3.w);
    int r = elem >> 8, c = elem & 255;
    int row = (tl & 15) * 256 + r;
    int col = 4096 + (tl >> 4) * 256 + c;
    *(ushort4*)&qkv[(size_t)row * 4608 + col] = o;
  } else {  // K/V low-rank injection
    float* Ml = (float*)tile;
    float* gl = ((float*)tile) + 256;
    const int bid = bidx - (576 + 2048);  // [0,4096)
    const int nb = bid & 63, t = (bid >> 6) & 3, h = (bid >> 8) & 7, b = bid >> 11;
    const int nl = tid >> 6, d = tid & 63;
    Ml[tid] = Mm[(size_t)(((b * 4 + t) * 256 + nb * 4) * 64) + tid];
    if (tid < 4) gl[tid] = Wr[(b * 4 + t) * 256 + nb * 4 + tid];
    __syncthreads();
    float ak = 0.f, av = 0.f;
#pragma unroll 8
    for (int f = 0; f < 64; ++f) {
      float mv = Ml[nl * 64 + f];
      ak += mv * Fk[(h * 64 + f) * 64 + d];
      av += mv * Fv[(h * 64 + f) * 64 + d];
    }
    float gate = gl[nl];
    ak *= gate; av *= gate;
    const int n = nb * 4 + nl;
    const size_t s0 = (size_t)(b * 2048 + t * 256 + n);
#pragma unroll
    for (int r = 0; r < 2; ++r) {
      size_t row = s0 + (size_t)r * 1024;
      size_t ik = row * 4608 + 1536 + h * 64 + d;
      qkv[ik] = f2b(b2f(qkv[ik]) + ak);
      size_t iv = row * 4608 + 3072 + h * 64 + d;
      qkv[iv] = f2b(b2f(qkv[iv]) + av);
    }
  }
}

// ---------------- standalone fallback kernels (no-split path) ----------------
__global__ __launch_bounds__(256) void k_transpose(const float* __restrict__ src,
                                                   unsigned short* __restrict__ dst) {
  __shared__ float tile[64][65];
  const int tx = threadIdx.x & 63, ty = threadIdx.x >> 6;
  const int r0 = (blockIdx.x / 24) * 64, c0 = (blockIdx.x % 24) * 64;
#pragma unroll
  for (int j = 0; j < 16; ++j)
    tile[ty + j * 4][tx] = src[(size_t)(r0 + ty + j * 4) * 1536 + c0 + tx];
  __syncthreads();
#pragma unroll
  for (int j = 0; j < 16; ++j)
    dst[(size_t)(c0 + ty + j * 4) * 1536 + r0 + tx] = f2b(tile[tx][ty + j * 4]);
}

__global__ __launch_bounds__(256) void k_inject(const float* __restrict__ Mm,
                                                const float* __restrict__ Wr,
                                                const float* __restrict__ Fk,
                                                const float* __restrict__ Fv,
                                                unsigned short* __restrict__ qkv) {
  __shared__ float Ml[256];
  __shared__ float gl[4];
  const int bid = blockIdx.x;
  const int nb = bid & 63, t = (bid >> 6) & 3, h = (bid >> 8) & 7, b = bid >> 11;
  const int tid = threadIdx.x;
  const int nl = tid >> 6, d = tid & 63;
  Ml[tid] = Mm[(size_t)(((b * 4 + t) * 256 + nb * 4) * 64) + tid];
  if (tid < 4) gl[tid] = Wr[(b * 4 + t) * 256 + nb * 4 + tid];
  __syncthreads();
  float ak = 0.f, av = 0.f;
#pragma unroll 8
  for (int f = 0; f < 64; ++f) {
    float mv = Ml[nl * 64 + f];
    ak += mv * Fk[(h * 64 + f) * 64 + d];
    av += mv * Fv[(h * 64 + f) * 64 + d];
  }
  float gate = gl[nl];
  ak *= gate; av *= gate;
  const int n = nb * 4 + nl;
  const size_t s0 = (size_t)(b * 2048 + t * 256 + n);
#pragma unroll
  for (int r = 0; r < 2; ++r) {
    size_t row = s0 + (size_t)r * 1024;
    size_t ik = row * 4608 + 1536 + h * 64 + d;
    qkv[ik] = f2b(b2f(qkv[ik]) + ak);
    size_t iv = row * 4608 + 3072 + h * 64 + d;
    qkv[iv] = f2b(b2f(qkv[iv]) + av);
  }
}

// ---------------- m201-style 8-phase 256x256 bf16 GEMM, BK=64, 128KB dyn LDS ----------
__global__ __launch_bounds__(512, 2) void k_gemm8(const unsigned short* __restrict__ A,
                                                  const unsigned short* __restrict__ BT,
                                                  unsigned short* __restrict__ C,
                                                  float* __restrict__ scratch,
                                                  int K, int gridNmain, int nMain) {
  extern __shared__ unsigned short lds[];
  unsigned short* As = lds;           // 4 slots x 8192 elems (16KB)
  unsigned short* Bs = lds + 32768;
  const int tid = threadIdx.x;
  const int lane = tid & 63, wave = tid >> 6;
  const int wm = wave >> 2, wn = wave & 3;
  const int r15 = lane & 15, g = lane >> 4;
  const int sw = r15 & 7;

  int bm, bn, kbeg, NT, slot;
  bool partial;
  if ((int)blockIdx.x < nMain) {
    int bid = blockIdx.x;
    int cpx = nMain >> 3;  // bijective XCD swizzle (nMain % 8 == 0)
    bid = (bid & 7) * cpx + (bid >> 3);
    bm = (bid / gridNmain) * 256;
    bn = (bid % gridNmain) * 256;
    kbeg = 0; NT = K >> 6; partial = false; slot = 0;
  } else {
    int s = blockIdx.x - nMain;       // [0,128)
    int tile = s >> 2, slice = s & 3;
    bm = (tile & 15) * 256;
    bn = 4096 + (tile >> 4) * 256;
    kbeg = slice * 384; NT = 6; partial = true; slot = s;
  }
  const unsigned short* Ab = A + kbeg;
  const unsigned short* BTb = BT + kbeg;

  f32x4 acc[8][4] = {};

  auto STAGE = [&](int tl, int part) {
    const bool isB = part >= 2;
    const int half = part & 1;
    const unsigned short* src = isB ? BTb : Ab;
    const int rb = (isB ? bn : bm) + half * 128;
    char* slotp = (char*)(isB ? Bs : As) + ((tl & 1) * 2 + half) * 16384;
#pragma unroll
    for (int i = 0; i < 2; ++i) {
      int cid = i * 512 + tid;
      int row = cid >> 3;
      int logc = (cid & 7) ^ (row & 7);
      gload_lds16(src + (size_t)(rb + row) * K + tl * 64 + logc * 8,
                  slotp + i * 8192 + wave * 1024);
    }
  };

  STAGE(0, 2); STAGE(0, 3); STAGE(0, 0); STAGE(0, 1);
  STAGE(1, 2); STAGE(1, 3); STAGE(1, 0);
  asm volatile("s_waitcnt vmcnt(6)" ::: "memory");
  __builtin_amdgcn_s_barrier();

  bf16x8 af[4][2], bf[4][2];
  for (int t = 0; t < NT; ++t) {
    const int d = t & 1;
    const unsigned short* Aslot = As + (d * 2 + wm) * 8192;
    const unsigned short* Bslot = Bs + (d * 2 + (wn >> 1)) * 8192;
    const int bro = (wn & 1) * 64;

#pragma unroll
    for (int j = 0; j < 4; ++j) {
      const unsigned short* ar = Aslot + (j * 16 + r15) * 64;
      af[j][0] = *(const bf16x8*)(ar + ((g ^ sw) * 8));
      af[j][1] = *(const bf16x8*)(ar + (((4 + g) ^ sw) * 8));
    }
#pragma unroll
    for (int n = 0; n < 2; ++n) {
      const unsigned short* br = Bslot + (bro + n * 16 + r15) * 64;
      bf[n][0] = *(const bf16x8*)(br + ((g ^ sw) * 8));
      bf[n][1] = *(const bf16x8*)(br + (((4 + g) ^ sw) * 8));
    }
    if (t + 1 < NT) STAGE(t + 1, 1);
    __builtin_amdgcn_s_barrier();
    asm volatile("s_waitcnt lgkmcnt(0)" ::: "memory");
    __builtin_amdgcn_sched_barrier(0);
    __builtin_amdgcn_s_setprio(1);
#pragma unroll
    for (int j = 0; j < 4; ++j)
#pragma unroll
      for (int n = 0; n < 2; ++n) {
        acc[j][n] = mfma16(af[j][0], bf[n][0], acc[j][n]);
        acc[j][n] = mfma16(af[j][1], bf[n][1], acc[j][n]);
      }
    __builtin_amdgcn_s_setprio(0);
    __builtin_amdgcn_s_barrier();

#pragma unroll
    for (int n = 2; n < 4; ++n) {
      const unsigned short* br = Bslot + (bro + n * 16 + r15) * 64;
      bf[n][0] = *(const bf16x8*)(br + ((g ^ sw) * 8));
      bf[n][1] = *(const bf16x8*)(br + (((4 + g) ^ sw) * 8));
    }
    __builtin_amdgcn_s_barrier();
    asm volatile("s_waitcnt lgkmcnt(0)" ::: "memory");
    __builtin_amdgcn_sched_barrier(0);
    __builtin_amdgcn_s_setprio(1);
#pragma unroll
    for (int j = 0; j < 4; ++j)
#pragma unroll
      for (int n = 2; n < 4; ++n) {
        acc[j][n] = mfma16(af[j][0], bf[n][0], acc[j][n]);
        acc[j][n] = mfma16(af[j][1], bf[n][1], acc[j][n]);
      }
    __builtin_amdgcn_s_setprio(0);
    __builtin_amdgcn_s_barrier();

#pragma unroll
    for (int j = 0; j < 4; ++j) {
      const unsigned short* ar = Aslot + (64 + j * 16 + r15) * 64;
      af[j][0] = *(const bf16x8*)(ar + ((g ^ sw) * 8));
      af[j][1] = *(const bf16x8*)(ar + (((4 + g) ^ sw) * 8));
    }
    if (t + 2 < NT) STAGE(t + 2, 2);
    __builtin_amdgcn_s_barrier();
    asm volatile("s_waitcnt lgkmcnt(0)" ::: "memory");
    __builtin_amdgcn_sched_barrier(0);
    __builtin_amdgcn_s_setprio(1);
#pragma unroll
    for (int j = 0; j < 4; ++j)
#pragma unroll
      for (int n = 0; n < 2; ++n) {
        acc[4 + j][n] = mfma16(af[j][0], bf[n][0], acc[4 + j][n]);
        acc[4 + j][n] = mfma16(af[j][1], bf[n][1], acc[4 + j][n]);
      }
    __builtin_amdgcn_s_setprio(0);
    __builtin_amdgcn_s_barrier();

    if (t + 2 < NT) { STAGE(t + 2, 3); STAGE(t + 2, 0); }
    __builtin_amdgcn_s_barrier();
    __builtin_amdgcn_s_setprio(1);
#pragma unroll
    for (int j = 0; j < 4; ++j)
#pragma unroll
      for (int n = 2; n < 4; ++n) {
        acc[4 + j][n] = mfma16(af[j][0], bf[n][0], acc[4 + j][n]);
        acc[4 + j][n] = mfma16(af[j][1], bf[n][1], acc[4 + j][n]);
      }
    __builtin_amdgcn_s_setprio(0);
    if (t < NT - 2)
      asm volatile("s_waitcnt vmcnt(6)" ::: "memory");
    else
      asm volatile("s_waitcnt vmcnt(0)" ::: "memory");
    __builtin_amdgcn_s_barrier();
  }

  // epilogue
  if (!partial) {
#pragma unroll
    for (int m = 0; m < 8; ++m)
#pragma unroll
      for (int n = 0; n < 4; ++n)
#pragma unroll
        for (int i = 0; i < 4; ++i) {
          int row = bm + wm * 128 + m * 16 + g * 4 + i;
          int col = bn + wn * 64 + n * 16 + r15;
          C[(size_t)row * 4608 + col] = f2b(acc[m][n][i]);
        }
  } else {
    float* sp = scratch + (size_t)slot * 65536;
#pragma unroll
    for (int m = 0; m < 8; ++m)
#pragma unroll
      for (int n = 0; n < 4; ++n)
#pragma unroll
        for (int i = 0; i < 4; ++i) {
          int rl = wm * 128 + m * 16 + g * 4 + i;
          int cl = wn * 64 + n * 16 + r15;
          sp[rl * 256 + cl] = acc[m][n][i];
        }
  }
}

// ---------------- strip fixup (fallback standalone; fused copy in k_post) ----------
__global__ __launch_bounds__(256) void k_fixup(const float* __restrict__ scratch,
                                               unsigned short* __restrict__ qkv) {
  size_t gid = (size_t)blockIdx.x * 256 + threadIdx.x;
  int tile = (int)(gid >> 14);
  int elem = (int)(gid & 16383) * 4;
  const float* base = scratch + (size_t)tile * 4 * 65536;
  float4 p0 = *(const float4*)(base + elem);
  float4 p1 = *(const float4*)(base + 65536 + elem);
  float4 p2 = *(const float4*)(base + 131072 + elem);
  float4 p3 = *(const float4*)(base + 196608 + elem);
  ushort4 o;
  o.x = f2b(p0.x + p1.x + p2.x + p3.x);
  o.y = f2b(p0.y + p1.y + p2.y + p3.y);
  o.z = f2b(p0.z + p1.z + p2.z + p3.z);
  o.w = f2b(p0.w + p1.w + p2.w + p3.w);
  int r = elem >> 8, c = elem & 255;
  int row = (tile & 15) * 256 + r;
  int col = 4096 + (tile >> 4) * 256 + c;
  *(ushort4*)&qkv[(size_t)row * 4608 + col] = o;
}

// ---------------- output-projection GEMM: 128x64 tiles, 768 blocks (3/CU balanced) ----
// C(f32, +bias) = A(4096x1536 bf16) * BT(1536x1536 bf16)^T. m97 staging pattern
// (linear dest), 4 waves 2Mx2N (each 64x32), BK=32. Same per-output K-order as
// the previous 128x128 kernel -> bit-identical results.
__global__ __launch_bounds__(256) void k_gemm2(const unsigned short* __restrict__ A,
                                               const unsigned short* __restrict__ BT,
                                               float* __restrict__ C,
                                               const float* __restrict__ bias) {
  __shared__ unsigned short As[128 * 32];  // 8 KB
  __shared__ unsigned short Bs[64 * 32];   // 4 KB
  const int tid = threadIdx.x;
  const int lane = tid & 63, wave = tid >> 6;
  int bidx = blockIdx.x;
  {  // bijective XCD swizzle (768 % 8 == 0)
    int cpx = gridDim.x >> 3;
    bidx = (bidx & 7) * cpx + (bidx >> 3);
  }
  const int bm = (bidx / 24) * 128;
  const int bn = (bidx % 24) * 64;
  const int wr = (wave >> 1) * 64, wc = (wave & 1) * 32;
  const int r15 = lane & 15, g = lane >> 4;
  const int row0 = tid >> 2, c0 = tid & 3;
  const int K = 1536;

  f32x4 acc[4][2] = {};

  for (int k0 = 0; k0 < K; k0 += 32) {
    __syncthreads();
    gload_lds16(A + (size_t)(bm + row0) * K + k0 + c0 * 8, (char*)As + wave * 1024);
    gload_lds16(A + (size_t)(bm + row0 + 64) * K + k0 + c0 * 8,
                (char*)As + 4096 + wave * 1024);
    gload_lds16(BT + (size_t)(bn + row0) * K + k0 + c0 * 8, (char*)Bs + wave * 1024);
    __syncthreads();
    bf16x8 af[4], bfr[2];
#pragma unroll
    for (int m = 0; m < 4; ++m)
      af[m] = *(const bf16x8*)&As[(wr + m * 16 + r15) * 32 + g * 8];
#pragma unroll
    for (int n = 0; n < 2; ++n)
      bfr[n] = *(const bf16x8*)&Bs[(wc + n * 16 + r15) * 32 + g * 8];
#pragma unroll
    for (int m = 0; m < 4; ++m)
#pragma unroll
      for (int n = 0; n < 2; ++n)
        acc[m][n] = mfma16(af[m], bfr[n], acc[m][n]);
  }

#pragma unroll
  for (int m = 0; m < 4; ++m)
#pragma unroll
    for (int n = 0; n < 2; ++n)
#pragma unroll
      for (int i = 0; i < 4; ++i) {
        int row = bm + wr + m * 16 + g * 4 + i;
        int col = bn + wc + n * 16 + r15;
        C[(size_t)row * 1536 + col] = acc[m][n][i] + bias[col];
      }
}

// ---------------- flash attention, swapped QK^T, P-in-register ----------------
// Round-16 version (77.9us): max3 tree + l-via-MFMA (ones fragment), stride 72.
__global__ __launch_bounds__(256, 3) void k_attn(const unsigned short* __restrict__ qkv,
                                                 unsigned short* __restrict__ attno) {
  __shared__ unsigned short Kl[2 * 64 * 64];   // 16 KB
  __shared__ unsigned short VT[2 * 64 * 72];   // 18 KB
  const int tid = threadIdx.x;
  const int lane = tid & 63, wave = tid >> 6;
  const int bid = blockIdx.x;  // 768 = B*24*16
  const int qt = bid & 15;
  const int h = (bid >> 4) % 24;
  const int b = (bid >> 4) / 24;
  const int r15 = lane & 15, g = lane >> 4;
  const int q0 = qt * 128 + wave * 32;
  const size_t RS = 4608;
  const size_t tokbase = (size_t)(b * 2048);

  bf16x8 qb[2][2];
  {
    const float qs = 0.125f * LOG2E;
#pragma unroll
    for (int qh = 0; qh < 2; ++qh) {
      const unsigned short* qrow = qkv + (tokbase + q0 + qh * 16 + r15) * RS + h * 64;
#pragma unroll
      for (int kk = 0; kk < 2; ++kk) {
        bf16x8 v = *(const bf16x8*)(qrow + kk * 32 + g * 8);
#pragma unroll
        for (int e = 0; e < 8; ++e)
          v[e] = (short)f2b(b2f((unsigned short)v[e]) * qs);
        qb[qh][kk] = v;
      }
    }
  }
  bf16x8 ones;
#pragma unroll
  for (int e = 0; e < 8; ++e) ones[e] = (short)0x3F80;  // bf16 1.0

  f32x4 o[2][4] = {};
  f32x4 l_acc[2] = {};
  float m_run[2] = {-1e30f, -1e30f};
  bf16x8 vr[2];

  const int ch0 = wave * 2 * 64 + lane, ch1 = (wave * 2 + 1) * 64 + lane;
  const int kr0 = ch0 >> 3, kc0s = ((ch0 & 7) ^ (kr0 & 7)) * 8;
  const int kr1 = ch1 >> 3, kc1s = ((ch1 & 7) ^ (kr1 & 7)) * 8;
  const int kcol = ((lane >> 5) & 1) * 32 + ((lane >> 2) & 3) * 8 +
                   ((lane >> 4) & 1) * 4 + (lane & 3);

#define STAGE_K(buf, kv0)                                                          \
  {                                                                                \
    gload_lds16(qkv + (tokbase + (kv0) + kr0) * RS + 1536 + h * 64 + kc0s,         \
                (char*)Kl + (buf) * 8192 + (wave * 2) * 1024);                     \
    gload_lds16(qkv + (tokbase + (kv0) + kr1) * RS + 1536 + h * 64 + kc1s,         \
                (char*)Kl + (buf) * 8192 + (wave * 2 + 1) * 1024);                 \
  }
#define LOAD_V(kv0)                                                                \
  {                                                                                \
    const unsigned short* vrow = qkv + (tokbase + (kv0) + lane) * RS + 3072 + h * 64; \
    vr[0] = *(const bf16x8*)(vrow + (wave * 2) * 8);                               \
    vr[1] = *(const bf16x8*)(vrow + (wave * 2 + 1) * 8);                           \
  }
#define WRITE_V(buf)                                                               \
  {                                                                                \
    _Pragma("unroll") for (int s = 0; s < 2; ++s) {                                \
      int d0 = (wave * 2 + s) * 8;                                                 \
      _Pragma("unroll") for (int e = 0; e < 8; ++e)                                \
          VT[(buf) * 4608 + (d0 + e) * 72 + kcol] = (unsigned short)vr[s][e];      \
    }                                                                              \
  }

  STAGE_K(0, 0);
  LOAD_V(0);
  asm volatile("s_waitcnt vmcnt(0)" ::: "memory");
  WRITE_V(0);
  __syncthreads();

  int cur = 0;
  for (int t = 0; t < 32; ++t) {
    const int kv0 = t * 64;
    if (t < 31) {
      STAGE_K(cur ^ 1, kv0 + 64);
      LOAD_V(kv0 + 64);
    }

    f32x4 st[4][2];
    const unsigned short* Kb = Kl + cur * 4096;
    __builtin_amdgcn_s_setprio(1);
#pragma unroll
    for (int m = 0; m < 4; ++m) {
      int row = m * 16 + r15;
      int r7 = row & 7;
      bf16x8 ka0 = *(const bf16x8*)&Kb[row * 64 + ((g ^ r7) * 8)];
      bf16x8 ka1 = *(const bf16x8*)&Kb[row * 64 + (((4 + g) ^ r7) * 8)];
#pragma unroll
      for (int qh = 0; qh < 2; ++qh) {
        f32x4 z = {0.f, 0.f, 0.f, 0.f};
        st[m][qh] = mfma16(ka0, qb[qh][0], z);
        st[m][qh] = mfma16(ka1, qb[qh][1], st[m][qh]);
      }
    }
    __builtin_amdgcn_s_setprio(0);

    float pm[2];
#pragma unroll
    for (int qh = 0; qh < 2; ++qh) {
      float t0 = max3f(st[0][qh][0], st[0][qh][1], st[0][qh][2]);
      float t1 = max3f(st[0][qh][3], st[1][qh][0], st[1][qh][1]);
      float t2 = max3f(st[1][qh][2], st[1][qh][3], st[2][qh][0]);
      float t3 = max3f(st[2][qh][1], st[2][qh][2], st[2][qh][3]);
      float t4 = max3f(st[3][qh][0], st[3][qh][1], st[3][qh][2]);
      float p = fmaxf(max3f(t0, t1, t2), max3f(t3, t4, st[3][qh][3]));
      p = fmaxf(p, __shfl_xor(p, 16, 64));
      pm[qh] = fmaxf(p, __shfl_xor(p, 32, 64));
    }

    if (!__all(pm[0] - m_run[0] <= 8.0f && pm[1] - m_run[1] <= 8.0f)) {
#pragma unroll
      for (int qh = 0; qh < 2; ++qh) {
        float mnew = fmaxf(m_run[qh], pm[qh]);
        float fac = fexp2(m_run[qh] - mnew);
        float f_i[4];
#pragma unroll
        for (int i = 0; i < 4; ++i)
          f_i[i] = __shfl(fac, (lane & 48) | ((((lane >> 4) & 3) << 2) + i), 64);
#pragma unroll
        for (int dt = 0; dt < 4; ++dt)
#pragma unroll
          for (int i = 0; i < 4; ++i) o[qh][dt][i] *= f_i[i];
#pragma unroll
        for (int i = 0; i < 4; ++i) l_acc[qh][i] *= f_i[i];
        m_run[qh] = mnew;
      }
    }

    unsigned pku[2][4][2];
#pragma unroll
    for (int m = 0; m < 4; ++m)
#pragma unroll
      for (int qh = 0; qh < 2; ++qh) {
        float p0 = fexp2(st[m][qh][0] - m_run[qh]);
        float p1 = fexp2(st[m][qh][1] - m_run[qh]);
        float p2 = fexp2(st[m][qh][2] - m_run[qh]);
        float p3 = fexp2(st[m][qh][3] - m_run[qh]);
        pku[qh][m][0] = cvtpk(p0, p1);
        pku[qh][m][1] = cvtpk(p2, p3);
      }

    const unsigned short* Vb = VT + cur * 4608;
    __builtin_amdgcn_s_setprio(1);
#pragma unroll
    for (int kap = 0; kap < 2; ++kap) {
      union { bf16x8 v; unsigned u[4]; } pa0, pa1;
      pa0.u[0] = pku[0][2 * kap][0];     pa0.u[1] = pku[0][2 * kap][1];
      pa0.u[2] = pku[0][2 * kap + 1][0]; pa0.u[3] = pku[0][2 * kap + 1][1];
      pa1.u[0] = pku[1][2 * kap][0];     pa1.u[1] = pku[1][2 * kap][1];
      pa1.u[2] = pku[1][2 * kap + 1][0]; pa1.u[3] = pku[1][2 * kap + 1][1];
#pragma unroll
      for (int dt = 0; dt < 4; ++dt) {
        bf16x8 vb = *(const bf16x8*)&Vb[(dt * 16 + r15) * 72 + kap * 32 + g * 8];
        o[0][dt] = mfma16(pa0.v, vb, o[0][dt]);
        o[1][dt] = mfma16(pa1.v, vb, o[1][dt]);
      }
      l_acc[0] = mfma16(pa0.v, ones, l_acc[0]);
      l_acc[1] = mfma16(pa1.v, ones, l_acc[1]);
    }
    __builtin_amdgcn_s_setprio(0);

    if (t < 31) {
      asm volatile("s_waitcnt vmcnt(0)" ::: "memory");
      WRITE_V(cur ^ 1);
    }
    __syncthreads();
    cur ^= 1;
  }

#pragma unroll
  for (int qh = 0; qh < 2; ++qh) {
    float r_i[4];
#pragma unroll
    for (int i = 0; i < 4; ++i) r_i[i] = 1.0f / l_acc[qh][i];
#pragma unroll
    for (int dt = 0; dt < 4; ++dt)
#pragma unroll
      for (int i = 0; i < 4; ++i) {
        int q = q0 + qh * 16 + ((lane >> 4) << 2) + i;
        int col = h * 64 + dt * 16 + r15;
        attno[(tokbase + q) * 1536 + col] = f2b(o[qh][dt][i] * r_i[i]);
      }
  }
}

extern "C" void kernel_launch(void* const* d_in, const int* in_sizes, int n_in,
                              void* d_out, int out_size, void* d_ws, size_t ws_size,
                              hipStream_t stream) {
  const float* hs = (const float*)d_in[0];
  const float* Wq = (const float*)d_in[1];
  const float* Wk = (const float*)d_in[2];
  const float* Wv = (const float*)d_in[3];
  const float* Wo = (const float*)d_in[4];
  const float* bo = (const float*)d_in[5];
  const float* Mm = (const float*)d_in[6];
  const float* Wr = (const float*)d_in[7];
  const float* Fk = (const float*)d_in[8];
  const float* Fv = (const float*)d_in[9];
  float* out = (float*)d_out;

  unsigned short* hsb   = (unsigned short*)d_ws;
  unsigned short* wqkvt = hsb + (size_t)4096 * 1536;
  unsigned short* qkv   = wqkvt + (size_t)4608 * 1536;
  unsigned short* attno = hsb;
  unsigned short* wot   = wqkvt;

  const size_t base_bytes = ((size_t)4096 * 1536 + (size_t)4608 * 1536 +
                             (size_t)4096 * 4608) * 2;  // 64.49 MB
  float* scratch = (float*)((char*)d_ws + base_bytes);
  const bool split = ws_size >= base_bytes + (size_t)128 * 65536 * 4;

  hipFuncSetAttribute((const void*)k_gemm8,
                      hipFuncAttributeMaxDynamicSharedMemorySize, 131072);

  k_pre<<<7872, 256, 0, stream>>>(hs, Wq, Wk, Wv, hsb, wqkvt);

  if (split) {
    k_gemm8<<<384, 512, 131072, stream>>>(hsb, wqkvt, qkv, scratch, 1536, 16, 256);
    k_post<<<6720, 256, 0, stream>>>(Wo, wot, scratch, qkv, Mm, Wr, Fk, Fv);
  } else {
    k_gemm8<<<288, 512, 131072, stream>>>(hsb, wqkvt, qkv, (float*)nullptr, 1536, 18, 288);
    k_transpose<<<576, 256, 0, stream>>>(Wo, wot);
    k_inject<<<4096, 256, 0, stream>>>(Mm, Wr, Fk, Fv, qkv);
  }
  k_attn<<<768, 256, 0, stream>>>(qkv, attno);    // attno aliases hsb
  k_gemm2<<<768, 256, 0, stream>>>(attno, wot, out, bo);
}